// Round 11
// baseline (344.278 us; speedup 1.0000x reference)
//
#include <hip/hip_runtime.h>
#include <math.h>

// Model_6150393168181 — fully bf16-MFMA pipeline.
// out[b] = (1/sqrt(128)) * sum_w (f qsa_w^T) (S_w f ksa_w^T)^T
//        = (1/sqrt(128)) * sum_w (f MB_w^T) f^T ... restructured:
//   MB_w[o][d] = sum_{o'} ksa[w,o',o] qsa[w,o',d]   (precomputed, bf16)
//   G_w = f @ MB_w(as B)   P_w = G_w @ f^T   out += P_w @ SB_w^T
// All three stages are row-parallel -> attn grid = 256 batches x 2 row-halves.
// f = rms(relu(SAGE4(rms(flows)))); SAGE agg via corr_l = L @ (X_l @ wl_l^T) (chain0_k).

typedef __attribute__((ext_vector_type(8))) short bf16x8;
typedef __attribute__((ext_vector_type(4))) float f32x4;

__device__ inline ushort f2b(float x) {
  unsigned u = __builtin_bit_cast(unsigned, x);
  unsigned r = (u + 0x7fffu + ((u >> 16) & 1u)) >> 16;
  return (ushort)r;
}

// ---------------- prep: SB reorder + SAGE weight conversions ----------------
__global__ __launch_bounds__(256) void prep_all_k(
    const float* __restrict__ s2w,
    const float* __restrict__ wl1, const float* __restrict__ wl2,
    const float* __restrict__ wl3, const float* __restrict__ wl4,
    const float* __restrict__ wr1, const float* __restrict__ wr2,
    const float* __restrict__ wr3, const float* __restrict__ wr4,
    ushort* __restrict__ SB, ushort* __restrict__ WL, ushort* __restrict__ WR) {
  int i = blockIdx.x * 256 + threadIdx.x;
  if (i < 131072) {
    int w = i >> 14, p = (i >> 7) & 127, m = i & 127;
    SB[i] = f2b(s2w[p * 1024 + m * 8 + w]);
    return;
  }
  i -= 131072;
  if (i < 98304) {
    float v, u;
    if      (i < 16384) { v = wl1[i];         u = wr1[i]; }
    else if (i < 49152) { v = wl2[i - 16384]; u = wr2[i - 16384]; }
    else if (i < 81920) { v = wl3[i - 49152]; u = wr3[i - 49152]; }
    else                { v = wl4[i - 81920]; u = wr4[i - 81920]; }
    WL[i] = f2b(v);
    WR[i] = f2b(u);
  }
}

// ---------------- prep: MB_w[o][d] = sum_{o'} ksa[w,o',o] * qsa[w,o',d] ----------------
__global__ __launch_bounds__(256, 1) void prep_mb_k(
    const float* __restrict__ qsa, const float* __restrict__ ksa,
    ushort* __restrict__ MB) {
  __shared__ char QT[32768];   // QT[d][o'] = qsa[w][o'][d]
  __shared__ char KTm[32768];  // KTm[o][o'] = ksa[w][o'][o]
  int w = blockIdx.x, tid = threadIdx.x;
  const float* qw = qsa + (size_t)w * 16384;
  const float* kw = ksa + (size_t)w * 16384;
  for (int e = tid; e < 16384; e += 256) {
    int op = e >> 7, c = e & 127;
    int off = c * 256 + ((op * 2) ^ ((c & 7) << 4));
    *reinterpret_cast<ushort*>(QT + off)  = f2b(qw[e]);
    *reinterpret_cast<ushort*>(KTm + off) = f2b(kw[e]);
  }
  __syncthreads();
  int l = tid & 63, wv = tid >> 6, lr = l & 15, lg = l >> 4;
  #pragma unroll
  for (int rt = 0; rt < 2; ++rt) {
    int o = wv * 32 + rt * 16 + lr;
    bf16x8 a[4];
    #pragma unroll
    for (int ks = 0; ks < 4; ++ks)
      a[ks] = *reinterpret_cast<const bf16x8*>(KTm + o * 256 + ((ks * 64 + lg * 16) ^ ((o & 7) << 4)));
    #pragma unroll
    for (int ct = 0; ct < 8; ++ct) {
      int d = ct * 16 + lr;
      bf16x8 bq[4];
      #pragma unroll
      for (int ks = 0; ks < 4; ++ks)
        bq[ks] = *reinterpret_cast<const bf16x8*>(QT + d * 256 + ((ks * 64 + lg * 16) ^ ((d & 7) << 4)));
      f32x4 acc = {0.f, 0.f, 0.f, 0.f};
      #pragma unroll
      for (int ks = 0; ks < 4; ++ks)
        acc = __builtin_amdgcn_mfma_f32_16x16x32_bf16(a[ks], bq[ks], acc, 0, 0, 0);
      #pragma unroll
      for (int r = 0; r < 4; ++r)
        MB[(size_t)w * 16384 + (wv * 32 + rt * 16 + lg * 4 + r) * 128 + ct * 16 + lr] = f2b(acc[r]);
    }
  }
}

// ---------------- stage 128 rows (chain0 only): raw bf16 + rms scale ----------------
__device__ inline void stage_flows128(const float* __restrict__ flows, int blk,
                                      char* Xt, float* sArr, int wv, int lane) {
  for (int r = 0; r < 32; ++r) {
    int row = wv * 32 + r;
    const float2 v = *reinterpret_cast<const float2*>(
        flows + ((size_t)blk * 128 + row) * 128 + lane * 2);
    float ss = v.x * v.x + v.y * v.y;
    ss += __shfl_xor(ss, 32); ss += __shfl_xor(ss, 16); ss += __shfl_xor(ss, 8);
    ss += __shfl_xor(ss, 4);  ss += __shfl_xor(ss, 2);  ss += __shfl_xor(ss, 1);
    unsigned pk = (unsigned)f2b(v.x) | ((unsigned)f2b(v.y) << 16);
    *reinterpret_cast<unsigned*>(Xt + row * 256 + ((lane * 4) ^ ((row & 7) << 4))) = pk;
    if (lane == 0) sArr[row] = rsqrtf(ss * (1.0f / 128.0f));
  }
}

// ---------------- stage 64 rows (sage_fused): 8 unrolled float4 loads per wave ----------------
__device__ inline void stage_flows64(const float* __restrict__ flows, int blk,
                                     char* Xt, float* sArr, int wv, int lane) {
  int r2 = lane >> 5;
  int c4 = lane & 31;
  #pragma unroll
  for (int it = 0; it < 8; ++it) {
    int rowbase = wv * 16 + it * 2;
    const float4 v = *reinterpret_cast<const float4*>(
        flows + ((size_t)blk * 64 + rowbase) * 128 + lane * 4);
    int row = rowbase + r2;
    float ss = v.x * v.x + v.y * v.y + v.z * v.z + v.w * v.w;
    ss += __shfl_xor(ss, 16); ss += __shfl_xor(ss, 8);
    ss += __shfl_xor(ss, 4);  ss += __shfl_xor(ss, 2); ss += __shfl_xor(ss, 1);
    uint2 pk;
    pk.x = (unsigned)f2b(v.x) | ((unsigned)f2b(v.y) << 16);
    pk.y = (unsigned)f2b(v.z) | ((unsigned)f2b(v.w) << 16);
    *reinterpret_cast<uint2*>(Xt + row * 256 + ((c4 * 8) ^ ((row & 7) << 4))) = pk;
    if (c4 == 0) sArr[row] = rsqrtf(ss * (1.0f / 128.0f));
  }
}

// ---------------- mid SAGE layer (64-row block) ----------------
template <int K, int N>
__device__ inline void sage_layer_mid64(char* Xt, const float* sP, float* sN,
                                        const ushort* __restrict__ Wr,
                                        const float* __restrict__ bias,
                                        const float* __restrict__ corr, bool useCorr,
                                        int wv, int lr, int lg) {
  __syncthreads();
  bf16x8 a[K / 32];
  float sr[4];
  int rowA = wv * 16 + lr;
  #pragma unroll
  for (int ks = 0; ks < K / 32; ++ks)
    a[ks] = *reinterpret_cast<const bf16x8*>(
        Xt + rowA * (K * 2) + ((ks * 64 + lg * 16) ^ ((rowA & 7) << 4)));
  #pragma unroll
  for (int rr = 0; rr < 4; ++rr) sr[rr] = sP[wv * 16 + 4 * lg + rr];
  __syncthreads();
  float ssq[4] = {0.f, 0.f, 0.f, 0.f};
  #pragma unroll
  for (int nt = 0; nt < N / 16; ++nt) {
    int col = nt * 16 + lr;
    bf16x8 b[K / 32];
    #pragma unroll
    for (int ks = 0; ks < K / 32; ++ks)
      b[ks] = *reinterpret_cast<const bf16x8*>(Wr + col * K + ks * 32 + lg * 8);
    f32x4 acc = {0.f, 0.f, 0.f, 0.f};
    #pragma unroll
    for (int ks = 0; ks < K / 32; ++ks)
      acc = __builtin_amdgcn_mfma_f32_16x16x32_bf16(a[ks], b[ks], acc, 0, 0, 0);
    float bb = bias[col];
    #pragma unroll
    for (int rr = 0; rr < 4; ++rr) {
      int row = wv * 16 + 4 * lg + rr;
      float y = acc[rr] * sr[rr] + bb;
      if (useCorr) y += corr[row * N + col];
      *reinterpret_cast<ushort*>(Xt + row * (N * 2) + ((col * 2) ^ ((row & 7) << 4))) = f2b(y);
      ssq[rr] += y * y;
    }
  }
  #pragma unroll
  for (int rr = 0; rr < 4; ++rr) {
    float ss = ssq[rr];
    ss += __shfl_xor(ss, 1); ss += __shfl_xor(ss, 2);
    ss += __shfl_xor(ss, 4); ss += __shfl_xor(ss, 8);
    if (lr == 0) sN[wv * 16 + 4 * lg + rr] = 1.0f / fmaxf(sqrtf(ss), 1e-12f);
  }
}

// ---------------- last SAGE layer (64-row block) ----------------
__device__ inline void sage_layer_last64(char* Xt, const float* sP,
                                         const ushort* __restrict__ Wr,
                                         const float* __restrict__ bias,
                                         const float* __restrict__ corr, bool useCorr,
                                         int wv, int lr, int lg,
                                         ushort* __restrict__ Fg, int blk) {
  __syncthreads();
  bf16x8 a[4];
  float sr[4];
  int rowA = wv * 16 + lr;
  #pragma unroll
  for (int ks = 0; ks < 4; ++ks)
    a[ks] = *reinterpret_cast<const bf16x8*>(
        Xt + rowA * 256 + ((ks * 64 + lg * 16) ^ ((rowA & 7) << 4)));
  #pragma unroll
  for (int rr = 0; rr < 4; ++rr) sr[rr] = sP[wv * 16 + 4 * lg + rr];
  __syncthreads();
  float yreg[8][4];
  float ssq[4] = {0.f, 0.f, 0.f, 0.f};
  #pragma unroll
  for (int nt = 0; nt < 8; ++nt) {
    int col = nt * 16 + lr;
    bf16x8 b[4];
    #pragma unroll
    for (int ks = 0; ks < 4; ++ks)
      b[ks] = *reinterpret_cast<const bf16x8*>(Wr + col * 128 + ks * 32 + lg * 8);
    f32x4 acc = {0.f, 0.f, 0.f, 0.f};
    #pragma unroll
    for (int ks = 0; ks < 4; ++ks)
      acc = __builtin_amdgcn_mfma_f32_16x16x32_bf16(a[ks], b[ks], acc, 0, 0, 0);
    float bb = bias[col];
    #pragma unroll
    for (int rr = 0; rr < 4; ++rr) {
      int row = wv * 16 + 4 * lg + rr;
      float y = acc[rr] * sr[rr] + bb;
      if (useCorr) y += corr[row * 128 + col];
      yreg[nt][rr] = y;
      ssq[rr] += y * y;
    }
  }
  float inv[4], sc[4];
  #pragma unroll
  for (int rr = 0; rr < 4; ++rr) {
    float ss = ssq[rr];
    ss += __shfl_xor(ss, 1); ss += __shfl_xor(ss, 2);
    ss += __shfl_xor(ss, 4); ss += __shfl_xor(ss, 8);
    inv[rr] = 1.0f / fmaxf(sqrtf(ss), 1e-12f);
  }
  float ss2[4] = {0.f, 0.f, 0.f, 0.f};
  #pragma unroll
  for (int nt = 0; nt < 8; ++nt)
    #pragma unroll
    for (int rr = 0; rr < 4; ++rr) {
      float v = fmaxf(yreg[nt][rr] * inv[rr], 0.f);
      yreg[nt][rr] = v;
      ss2[rr] += v * v;
    }
  #pragma unroll
  for (int rr = 0; rr < 4; ++rr) {
    float ss = ss2[rr];
    ss += __shfl_xor(ss, 1); ss += __shfl_xor(ss, 2);
    ss += __shfl_xor(ss, 4); ss += __shfl_xor(ss, 8);
    sc[rr] = sqrtf(128.0f / fmaxf(ss, 1e-20f));
  }
  #pragma unroll
  for (int nt = 0; nt < 8; ++nt)
    #pragma unroll
    for (int rr = 0; rr < 4; ++rr) {
      int row = wv * 16 + 4 * lg + rr;
      Fg[((size_t)blk * 64 + row) * 128 + nt * 16 + lr] = f2b(yreg[nt][rr] * sc[rr]);
    }
}

// ---------------- K2: fused SAGE, 512 blocks x 64 rows ----------------
__global__ __launch_bounds__(256, 2) void sage_fused(
    const float* __restrict__ flows, const ushort* __restrict__ WR,
    const float* __restrict__ bl1, const float* __restrict__ bl2,
    const float* __restrict__ bl3, const float* __restrict__ bl4,
    const float* __restrict__ C1, const float* __restrict__ C2,
    const float* __restrict__ C3, const float* __restrict__ C4,
    ushort* __restrict__ Fg) {
  __shared__ char Xt[32768];
  __shared__ float sA[64], sB[64];
  int blk = blockIdx.x, tid = threadIdx.x;
  int lane = tid & 63, wv = tid >> 6, lr = lane & 15, lg = lane >> 4;
  stage_flows64(flows, blk, Xt, sA, wv, lane);
  bool c = (blk < 2);
  int ro = c ? blk * 64 : 0;
  sage_layer_mid64<128, 128>(Xt, sA, sB, WR + 0,     bl1, C1 + ro * 128, c, wv, lr, lg);
  sage_layer_mid64<128, 256>(Xt, sB, sA, WR + 16384, bl2, C2 + ro * 256, c, wv, lr, lg);
  sage_layer_mid64<256, 128>(Xt, sA, sB, WR + 49152, bl3, C3 + ro * 128, c, wv, lr, lg);
  sage_layer_last64(Xt, sB, WR + 81920, bl4, C4 + ro * 128, c, wv, lr, lg, Fg, blk);
}

// ---------------- K1: batch-0 chain -> corr tables (128 rows, 1 block) ----------------
template <int K, int N, bool CORRONLY>
__device__ inline void chain_layer(char* Xt, char* C0T, const float* sP, float* sN,
                                   const ushort* __restrict__ Wl, const ushort* __restrict__ Wr,
                                   const float* __restrict__ bias, float* __restrict__ Cg,
                                   int wv, int lr, int lg) {
  __syncthreads();
  bf16x8 a[2][K / 32];
  float sr[2][4];
  #pragma unroll
  for (int m = 0; m < 2; ++m) {
    int rowA = wv * 32 + m * 16 + lr;
    #pragma unroll
    for (int ks = 0; ks < K / 32; ++ks)
      a[m][ks] = *reinterpret_cast<const bf16x8*>(
          Xt + rowA * (K * 2) + ((ks * 64 + lg * 16) ^ ((rowA & 7) << 4)));
    #pragma unroll
    for (int rr = 0; rr < 4; ++rr) sr[m][rr] = sP[wv * 32 + m * 16 + 4 * lg + rr];
  }
  __syncthreads();
  #pragma unroll
  for (int nt = 0; nt < N / 16; ++nt) {
    int col = nt * 16 + lr;
    bf16x8 b[K / 32];
    #pragma unroll
    for (int ks = 0; ks < K / 32; ++ks)
      b[ks] = *reinterpret_cast<const bf16x8*>(Wl + col * K + ks * 32 + lg * 8);
    f32x4 acc[2] = {{0.f, 0.f, 0.f, 0.f}, {0.f, 0.f, 0.f, 0.f}};
    #pragma unroll
    for (int ks = 0; ks < K / 32; ++ks) {
      acc[0] = __builtin_amdgcn_mfma_f32_16x16x32_bf16(a[0][ks], b[ks], acc[0], 0, 0, 0);
      acc[1] = __builtin_amdgcn_mfma_f32_16x16x32_bf16(a[1][ks], b[ks], acc[1], 0, 0, 0);
    }
    #pragma unroll
    for (int m = 0; m < 2; ++m)
      #pragma unroll
      for (int rr = 0; rr < 4; ++rr) {
        int row = wv * 32 + m * 16 + 4 * lg + rr;
        *reinterpret_cast<ushort*>(C0T + col * 256 + ((row * 2) ^ ((col & 7) << 4))) =
            f2b(acc[m][rr] * sr[m][rr]);
      }
  }
  __syncthreads();
  bf16x8 aL[2][4];
  #pragma unroll
  for (int m = 0; m < 2; ++m) {
    int rowL = wv * 32 + m * 16 + lr;
    ushort iv = f2b(1.0f / (float)(rowL > 1 ? rowL : 1));
    #pragma unroll
    for (int ks = 0; ks < 4; ++ks)
      #pragma unroll
      for (int j = 0; j < 8; ++j) {
        int k = ks * 32 + lg * 8 + j;
        aL[m][ks][j] = (short)((k < rowL) ? iv : 0);
      }
  }
  float ssq[2][4] = {{0.f, 0.f, 0.f, 0.f}, {0.f, 0.f, 0.f, 0.f}};
  #pragma unroll
  for (int nt = 0; nt < N / 16; ++nt) {
    int col = nt * 16 + lr;
    bf16x8 bc[4];
    #pragma unroll
    for (int ks = 0; ks < 4; ++ks)
      bc[ks] = *reinterpret_cast<const bf16x8*>(
          C0T + col * 256 + ((ks * 64 + lg * 16) ^ ((col & 7) << 4)));
    f32x4 cacc[2] = {{0.f, 0.f, 0.f, 0.f}, {0.f, 0.f, 0.f, 0.f}};
    #pragma unroll
    for (int ks = 0; ks < 4; ++ks) {
      cacc[0] = __builtin_amdgcn_mfma_f32_16x16x32_bf16(aL[0][ks], bc[ks], cacc[0], 0, 0, 0);
      cacc[1] = __builtin_amdgcn_mfma_f32_16x16x32_bf16(aL[1][ks], bc[ks], cacc[1], 0, 0, 0);
    }
    #pragma unroll
    for (int m = 0; m < 2; ++m)
      #pragma unroll
      for (int rr = 0; rr < 4; ++rr) {
        int row = wv * 32 + m * 16 + 4 * lg + rr;
        Cg[row * N + col] = cacc[m][rr];
      }
    if (!CORRONLY) {
      bf16x8 b[K / 32];
      #pragma unroll
      for (int ks = 0; ks < K / 32; ++ks)
        b[ks] = *reinterpret_cast<const bf16x8*>(Wr + col * K + ks * 32 + lg * 8);
      f32x4 acc[2] = {{0.f, 0.f, 0.f, 0.f}, {0.f, 0.f, 0.f, 0.f}};
      #pragma unroll
      for (int ks = 0; ks < K / 32; ++ks) {
        acc[0] = __builtin_amdgcn_mfma_f32_16x16x32_bf16(a[0][ks], b[ks], acc[0], 0, 0, 0);
        acc[1] = __builtin_amdgcn_mfma_f32_16x16x32_bf16(a[1][ks], b[ks], acc[1], 0, 0, 0);
      }
      float bb = bias[col];
      #pragma unroll
      for (int m = 0; m < 2; ++m)
        #pragma unroll
        for (int rr = 0; rr < 4; ++rr) {
          int row = wv * 32 + m * 16 + 4 * lg + rr;
          float y = acc[m][rr] * sr[m][rr] + bb + cacc[m][rr];
          *reinterpret_cast<ushort*>(Xt + row * (N * 2) + ((col * 2) ^ ((row & 7) << 4))) = f2b(y);
          ssq[m][rr] += y * y;
        }
    }
  }
  if (!CORRONLY) {
    #pragma unroll
    for (int m = 0; m < 2; ++m)
      #pragma unroll
      for (int rr = 0; rr < 4; ++rr) {
        float ss = ssq[m][rr];
        ss += __shfl_xor(ss, 1); ss += __shfl_xor(ss, 2);
        ss += __shfl_xor(ss, 4); ss += __shfl_xor(ss, 8);
        if (lr == 0) sN[wv * 32 + m * 16 + 4 * lg + rr] = 1.0f / fmaxf(sqrtf(ss), 1e-12f);
      }
  }
}

__global__ __launch_bounds__(256, 1) void chain0_k(
    const float* __restrict__ flows, const ushort* __restrict__ WL, const ushort* __restrict__ WR,
    const float* __restrict__ bl1, const float* __restrict__ bl2, const float* __restrict__ bl3,
    float* __restrict__ C1, float* __restrict__ C2, float* __restrict__ C3, float* __restrict__ C4) {
  __shared__ char Xt[65536];
  __shared__ char C0T[65536];
  __shared__ float sA[128], sB[128];
  int tid = threadIdx.x;
  int lane = tid & 63, wv = tid >> 6, lr = lane & 15, lg = lane >> 4;
  stage_flows128(flows, 0, Xt, sA, wv, lane);
  chain_layer<128, 128, false>(Xt, C0T, sA, sB, WL + 0,     WR + 0,     bl1, C1, wv, lr, lg);
  chain_layer<128, 256, false>(Xt, C0T, sB, sA, WL + 16384, WR + 16384, bl2, C2, wv, lr, lg);
  chain_layer<256, 128, false>(Xt, C0T, sA, sB, WL + 49152, WR + 49152, bl3, C3, wv, lr, lg);
  chain_layer<128, 128, true >(Xt, C0T, sB, sA, WL + 81920, WR + 81920, nullptr, C4, wv, lr, lg);
}

// ---------------- fused attention (M-route): 512 blocks = 256 batches x 2 halves ----------------
// Per block: 64 rows of f, 8 waves (4 row-tiles x 2 col-halves).
// Per worker w: A: G=f@MB_w -> Gl; bar; B: P=G@f^T -> Pl; bar; C: out += P@SB_w^T.
__global__ __launch_bounds__(512, 4) void attn_fused(
    const ushort* __restrict__ F, const ushort* __restrict__ MB,
    const ushort* __restrict__ SB, float* __restrict__ Out) {
  __shared__ char Gl[16384];
  __shared__ char Pl[16384];

  const int bh = blockIdx.x;
  const int b = bh >> 1, half = bh & 1;
  const int tid = threadIdx.x;
  const int l = tid & 63, wv = tid >> 6;
  const int wr = wv >> 1, wc = wv & 1;
  const int lr = l & 15, lg = l >> 4;

  const ushort* Fb = F + (size_t)b * 16384;
  const int nG = half * 64 + wr * 16;   // wave's global row-tile base
  const int nr = wr * 16 + lr;          // local A-frag row (0..63)

  // f A-fragments for this wave's 16 rows (persist across workers)
  bf16x8 fa[4];
  #pragma unroll
  for (int ks = 0; ks < 4; ++ks)
    fa[ks] = *reinterpret_cast<const bf16x8*>(Fb + (nG + lr) * 128 + ks * 32 + lg * 8);

  f32x4 oacc[4];
  #pragma unroll
  for (int j = 0; j < 4; ++j) oacc[j] = f32x4{0.f, 0.f, 0.f, 0.f};

  for (int w = 0; w < 8; ++w) {
    const ushort* mb = MB + w * 16384;
    const ushort* sb = SB + w * 16384;

    // ---- Phase A: G[n][o] = f @ MB_w, o in wave's 64-col half ----
    #pragma unroll
    for (int j = 0; j < 4; ++j) {
      int o = wc * 64 + j * 16 + lr;
      bf16x8 bm[4];
      #pragma unroll
      for (int ks = 0; ks < 4; ++ks)
        bm[ks] = *reinterpret_cast<const bf16x8*>(mb + o * 128 + ks * 32 + lg * 8);
      f32x4 g = {0.f, 0.f, 0.f, 0.f};
      #pragma unroll
      for (int ks = 0; ks < 4; ++ks)
        g = __builtin_amdgcn_mfma_f32_16x16x32_bf16(fa[ks], bm[ks], g, 0, 0, 0);
      int nb = wr * 16 + lg * 4;
      #pragma unroll
      for (int r = 0; r < 4; ++r) {
        int n = nb + r;
        *reinterpret_cast<ushort*>(Gl + n * 256 + ((o * 2) ^ ((n & 7) << 4))) = f2b(g[r]);
      }
    }
    __syncthreads();

    // ---- Phase B: P[n][m] = G @ f^T, m in wave's half ----
    bf16x8 ga[4];
    #pragma unroll
    for (int ks = 0; ks < 4; ++ks)
      ga[ks] = *reinterpret_cast<const bf16x8*>(Gl + nr * 256 + ((ks * 64 + lg * 16) ^ ((nr & 7) << 4)));
    #pragma unroll
    for (int j = 0; j < 4; ++j) {
      int m = wc * 64 + j * 16 + lr;
      bf16x8 bf_[4];
      #pragma unroll
      for (int ks = 0; ks < 4; ++ks)
        bf_[ks] = *reinterpret_cast<const bf16x8*>(Fb + m * 128 + ks * 32 + lg * 8);
      f32x4 p = {0.f, 0.f, 0.f, 0.f};
      #pragma unroll
      for (int ks = 0; ks < 4; ++ks)
        p = __builtin_amdgcn_mfma_f32_16x16x32_bf16(ga[ks], bf_[ks], p, 0, 0, 0);
      int nb = wr * 16 + lg * 4;
      #pragma unroll
      for (int r = 0; r < 4; ++r) {
        int n = nb + r;
        *reinterpret_cast<ushort*>(Pl + n * 256 + ((m * 2) ^ ((n & 7) << 4))) = f2b(p[r]);
      }
    }
    __syncthreads();

    // ---- Phase C: out += P @ SB_w^T, p-cols in wave's half ----
    // (no trailing barrier: next A writes Gl which nobody reads now; the post-A
    //  barrier of w+1 orders C's Pl reads before B_{w+1}'s Pl writes)
    bf16x8 pa[4];
    #pragma unroll
    for (int ks = 0; ks < 4; ++ks)
      pa[ks] = *reinterpret_cast<const bf16x8*>(Pl + nr * 256 + ((ks * 64 + lg * 16) ^ ((nr & 7) << 4)));
    #pragma unroll
    for (int j = 0; j < 4; ++j) {
      int p = wc * 64 + j * 16 + lr;
      bf16x8 bs[4];
      #pragma unroll
      for (int ks = 0; ks < 4; ++ks)
        bs[ks] = *reinterpret_cast<const bf16x8*>(sb + p * 128 + ks * 32 + lg * 8);
      #pragma unroll
      for (int ks = 0; ks < 4; ++ks)
        oacc[j] = __builtin_amdgcn_mfma_f32_16x16x32_bf16(pa[ks], bs[ks], oacc[j], 0, 0, 0);
    }
  }

  const float inv_scale = 0.08838834764831845f;
  float* ob = Out + (size_t)b * 16384;
  #pragma unroll
  for (int j = 0; j < 4; ++j) {
    int p = wc * 64 + j * 16 + lr;
    #pragma unroll
    for (int r = 0; r < 4; ++r)
      ob[(nG + lg * 4 + r) * 128 + p] = oacc[j][r] * inv_scale;
  }
}

extern "C" void kernel_launch(void* const* d_in, const int* in_sizes, int n_in,
                              void* d_out, int out_size, void* d_ws, size_t ws_size,
                              hipStream_t stream) {
  const float* flows = (const float*)d_in[0];
  const float* g1_wl = (const float*)d_in[10];
  const float* g1_bl = (const float*)d_in[11];
  const float* g1_wr = (const float*)d_in[12];
  const float* g2_wl = (const float*)d_in[13];
  const float* g2_bl = (const float*)d_in[14];
  const float* g2_wr = (const float*)d_in[15];
  const float* g3_wl = (const float*)d_in[16];
  const float* g3_bl = (const float*)d_in[17];
  const float* g3_wr = (const float*)d_in[18];
  const float* g4_wl = (const float*)d_in[19];
  const float* g4_bl = (const float*)d_in[20];
  const float* g4_wr = (const float*)d_in[21];
  const float* qsa   = (const float*)d_in[24];
  const float* ksa   = (const float*)d_in[25];
  const float* s2w   = (const float*)d_in[27];
  float* out = (float*)d_out;
  char* wsb  = (char*)d_ws;

  // workspace layout (bytes)
  ushort* FB16 = (ushort*)(wsb);                 // 32768*128 bf16 = 8388608
  ushort* SB   = (ushort*)(wsb + 8388608);       // 131072 bf16 = 262144
  ushort* WL   = (ushort*)(wsb + 8650752);       // 98304 bf16 = 196608
  ushort* WR   = (ushort*)(wsb + 8847360);       // 196608
  ushort* MBws = (ushort*)(wsb + 9043968);       // 131072 bf16 = 262144
  float*  C1   = (float*)(wsb + 9306112);        // 128*128 f32
  float*  C2   = (float*)(wsb + 9371648);        // 128*256 f32
  float*  C3   = (float*)(wsb + 9502720);
  float*  C4   = (float*)(wsb + 9568256);

  prep_all_k<<<896, 256, 0, stream>>>(s2w,
                                      g1_wl, g2_wl, g3_wl, g4_wl,
                                      g1_wr, g2_wr, g3_wr, g4_wr,
                                      SB, WL, WR);
  prep_mb_k<<<8, 256, 0, stream>>>(qsa, ksa, MBws);
  chain0_k<<<1, 256, 0, stream>>>(flows, WL, WR, g1_bl, g2_bl, g3_bl, C1, C2, C3, C4);
  sage_fused<<<512, 256, 0, stream>>>(flows, WR, g1_bl, g2_bl, g3_bl, g4_bl,
                                      C1, C2, C3, C4, FB16);
  attn_fused<<<512, 512, 0, stream>>>(FB16, MBws, SB, out);
}

// Round 12
// 318.945 us; speedup vs baseline: 1.0794x; 1.0794x over previous
//
#include <hip/hip_runtime.h>
#include <math.h>

// Model_6150393168181 — fully bf16-MFMA pipeline.
// out[b] = (1/sqrt(128)) * sum_w (f qsa_w^T) (S_w f ksa_w^T)^T
//        = (1/sqrt(128)) * sum_w (f MB_w^T) f^T ... restructured:
//   MB_w[o][d] = sum_{o'} ksa[w,o',o] qsa[w,o',d]   (precomputed, bf16)
//   G_w = f @ MB_w(as B)   P_w = G_w @ f^T   out += P_w @ SB_w^T
// attn grid = 256 batches x 2 row-halves; F tile staged in LDS (fix for the
// 137 MB FETCH regression: phase B re-read F from global per worker).
// f = rms(relu(SAGE4(rms(flows)))); SAGE agg via corr_l = L @ (X_l @ wl_l^T) (chain0_k).

typedef __attribute__((ext_vector_type(8))) short bf16x8;
typedef __attribute__((ext_vector_type(4))) float f32x4;

__device__ inline ushort f2b(float x) {
  unsigned u = __builtin_bit_cast(unsigned, x);
  unsigned r = (u + 0x7fffu + ((u >> 16) & 1u)) >> 16;
  return (ushort)r;
}

// ---------------- prep: SB reorder + SAGE weight conversions ----------------
__global__ __launch_bounds__(256) void prep_all_k(
    const float* __restrict__ s2w,
    const float* __restrict__ wl1, const float* __restrict__ wl2,
    const float* __restrict__ wl3, const float* __restrict__ wl4,
    const float* __restrict__ wr1, const float* __restrict__ wr2,
    const float* __restrict__ wr3, const float* __restrict__ wr4,
    ushort* __restrict__ SB, ushort* __restrict__ WL, ushort* __restrict__ WR) {
  int i = blockIdx.x * 256 + threadIdx.x;
  if (i < 131072) {
    int w = i >> 14, p = (i >> 7) & 127, m = i & 127;
    SB[i] = f2b(s2w[p * 1024 + m * 8 + w]);
    return;
  }
  i -= 131072;
  if (i < 98304) {
    float v, u;
    if      (i < 16384) { v = wl1[i];         u = wr1[i]; }
    else if (i < 49152) { v = wl2[i - 16384]; u = wr2[i - 16384]; }
    else if (i < 81920) { v = wl3[i - 49152]; u = wr3[i - 49152]; }
    else                { v = wl4[i - 81920]; u = wr4[i - 81920]; }
    WL[i] = f2b(v);
    WR[i] = f2b(u);
  }
}

// ---------------- prep: MB_w[o][d] = sum_{o'} ksa[w,o',o] * qsa[w,o',d] ----------------
__global__ __launch_bounds__(256, 1) void prep_mb_k(
    const float* __restrict__ qsa, const float* __restrict__ ksa,
    ushort* __restrict__ MB) {
  __shared__ char QT[32768];   // QT[d][o'] = qsa[w][o'][d]
  __shared__ char KTm[32768];  // KTm[o][o'] = ksa[w][o'][o]
  int w = blockIdx.x, tid = threadIdx.x;
  const float* qw = qsa + (size_t)w * 16384;
  const float* kw = ksa + (size_t)w * 16384;
  for (int e = tid; e < 16384; e += 256) {
    int op = e >> 7, c = e & 127;
    int off = c * 256 + ((op * 2) ^ ((c & 7) << 4));
    *reinterpret_cast<ushort*>(QT + off)  = f2b(qw[e]);
    *reinterpret_cast<ushort*>(KTm + off) = f2b(kw[e]);
  }
  __syncthreads();
  int l = tid & 63, wv = tid >> 6, lr = l & 15, lg = l >> 4;
  #pragma unroll
  for (int rt = 0; rt < 2; ++rt) {
    int o = wv * 32 + rt * 16 + lr;
    bf16x8 a[4];
    #pragma unroll
    for (int ks = 0; ks < 4; ++ks)
      a[ks] = *reinterpret_cast<const bf16x8*>(KTm + o * 256 + ((ks * 64 + lg * 16) ^ ((o & 7) << 4)));
    #pragma unroll
    for (int ct = 0; ct < 8; ++ct) {
      int d = ct * 16 + lr;
      bf16x8 bq[4];
      #pragma unroll
      for (int ks = 0; ks < 4; ++ks)
        bq[ks] = *reinterpret_cast<const bf16x8*>(QT + d * 256 + ((ks * 64 + lg * 16) ^ ((d & 7) << 4)));
      f32x4 acc = {0.f, 0.f, 0.f, 0.f};
      #pragma unroll
      for (int ks = 0; ks < 4; ++ks)
        acc = __builtin_amdgcn_mfma_f32_16x16x32_bf16(a[ks], bq[ks], acc, 0, 0, 0);
      #pragma unroll
      for (int r = 0; r < 4; ++r)
        MB[(size_t)w * 16384 + (wv * 32 + rt * 16 + lg * 4 + r) * 128 + ct * 16 + lr] = f2b(acc[r]);
    }
  }
}

// ---------------- stage 128 rows (chain0 only): raw bf16 + rms scale ----------------
__device__ inline void stage_flows128(const float* __restrict__ flows, int blk,
                                      char* Xt, float* sArr, int wv, int lane) {
  for (int r = 0; r < 32; ++r) {
    int row = wv * 32 + r;
    const float2 v = *reinterpret_cast<const float2*>(
        flows + ((size_t)blk * 128 + row) * 128 + lane * 2);
    float ss = v.x * v.x + v.y * v.y;
    ss += __shfl_xor(ss, 32); ss += __shfl_xor(ss, 16); ss += __shfl_xor(ss, 8);
    ss += __shfl_xor(ss, 4);  ss += __shfl_xor(ss, 2);  ss += __shfl_xor(ss, 1);
    unsigned pk = (unsigned)f2b(v.x) | ((unsigned)f2b(v.y) << 16);
    *reinterpret_cast<unsigned*>(Xt + row * 256 + ((lane * 4) ^ ((row & 7) << 4))) = pk;
    if (lane == 0) sArr[row] = rsqrtf(ss * (1.0f / 128.0f));
  }
}

// ---------------- stage 64 rows (sage_fused): 8 unrolled float4 loads per wave ----------------
__device__ inline void stage_flows64(const float* __restrict__ flows, int blk,
                                     char* Xt, float* sArr, int wv, int lane) {
  int r2 = lane >> 5;
  int c4 = lane & 31;
  #pragma unroll
  for (int it = 0; it < 8; ++it) {
    int rowbase = wv * 16 + it * 2;
    const float4 v = *reinterpret_cast<const float4*>(
        flows + ((size_t)blk * 64 + rowbase) * 128 + lane * 4);
    int row = rowbase + r2;
    float ss = v.x * v.x + v.y * v.y + v.z * v.z + v.w * v.w;
    ss += __shfl_xor(ss, 16); ss += __shfl_xor(ss, 8);
    ss += __shfl_xor(ss, 4);  ss += __shfl_xor(ss, 2); ss += __shfl_xor(ss, 1);
    uint2 pk;
    pk.x = (unsigned)f2b(v.x) | ((unsigned)f2b(v.y) << 16);
    pk.y = (unsigned)f2b(v.z) | ((unsigned)f2b(v.w) << 16);
    *reinterpret_cast<uint2*>(Xt + row * 256 + ((c4 * 8) ^ ((row & 7) << 4))) = pk;
    if (c4 == 0) sArr[row] = rsqrtf(ss * (1.0f / 128.0f));
  }
}

// ---------------- mid SAGE layer (64-row block) ----------------
template <int K, int N>
__device__ inline void sage_layer_mid64(char* Xt, const float* sP, float* sN,
                                        const ushort* __restrict__ Wr,
                                        const float* __restrict__ bias,
                                        const float* __restrict__ corr, bool useCorr,
                                        int wv, int lr, int lg) {
  __syncthreads();
  bf16x8 a[K / 32];
  float sr[4];
  int rowA = wv * 16 + lr;
  #pragma unroll
  for (int ks = 0; ks < K / 32; ++ks)
    a[ks] = *reinterpret_cast<const bf16x8*>(
        Xt + rowA * (K * 2) + ((ks * 64 + lg * 16) ^ ((rowA & 7) << 4)));
  #pragma unroll
  for (int rr = 0; rr < 4; ++rr) sr[rr] = sP[wv * 16 + 4 * lg + rr];
  __syncthreads();
  float ssq[4] = {0.f, 0.f, 0.f, 0.f};
  #pragma unroll
  for (int nt = 0; nt < N / 16; ++nt) {
    int col = nt * 16 + lr;
    bf16x8 b[K / 32];
    #pragma unroll
    for (int ks = 0; ks < K / 32; ++ks)
      b[ks] = *reinterpret_cast<const bf16x8*>(Wr + col * K + ks * 32 + lg * 8);
    f32x4 acc = {0.f, 0.f, 0.f, 0.f};
    #pragma unroll
    for (int ks = 0; ks < K / 32; ++ks)
      acc = __builtin_amdgcn_mfma_f32_16x16x32_bf16(a[ks], b[ks], acc, 0, 0, 0);
    float bb = bias[col];
    #pragma unroll
    for (int rr = 0; rr < 4; ++rr) {
      int row = wv * 16 + 4 * lg + rr;
      float y = acc[rr] * sr[rr] + bb;
      if (useCorr) y += corr[row * N + col];
      *reinterpret_cast<ushort*>(Xt + row * (N * 2) + ((col * 2) ^ ((row & 7) << 4))) = f2b(y);
      ssq[rr] += y * y;
    }
  }
  #pragma unroll
  for (int rr = 0; rr < 4; ++rr) {
    float ss = ssq[rr];
    ss += __shfl_xor(ss, 1); ss += __shfl_xor(ss, 2);
    ss += __shfl_xor(ss, 4); ss += __shfl_xor(ss, 8);
    if (lr == 0) sN[wv * 16 + 4 * lg + rr] = 1.0f / fmaxf(sqrtf(ss), 1e-12f);
  }
}

// ---------------- last SAGE layer (64-row block) ----------------
__device__ inline void sage_layer_last64(char* Xt, const float* sP,
                                         const ushort* __restrict__ Wr,
                                         const float* __restrict__ bias,
                                         const float* __restrict__ corr, bool useCorr,
                                         int wv, int lr, int lg,
                                         ushort* __restrict__ Fg, int blk) {
  __syncthreads();
  bf16x8 a[4];
  float sr[4];
  int rowA = wv * 16 + lr;
  #pragma unroll
  for (int ks = 0; ks < 4; ++ks)
    a[ks] = *reinterpret_cast<const bf16x8*>(
        Xt + rowA * 256 + ((ks * 64 + lg * 16) ^ ((rowA & 7) << 4)));
  #pragma unroll
  for (int rr = 0; rr < 4; ++rr) sr[rr] = sP[wv * 16 + 4 * lg + rr];
  __syncthreads();
  float yreg[8][4];
  float ssq[4] = {0.f, 0.f, 0.f, 0.f};
  #pragma unroll
  for (int nt = 0; nt < 8; ++nt) {
    int col = nt * 16 + lr;
    bf16x8 b[4];
    #pragma unroll
    for (int ks = 0; ks < 4; ++ks)
      b[ks] = *reinterpret_cast<const bf16x8*>(Wr + col * 128 + ks * 32 + lg * 8);
    f32x4 acc = {0.f, 0.f, 0.f, 0.f};
    #pragma unroll
    for (int ks = 0; ks < 4; ++ks)
      acc = __builtin_amdgcn_mfma_f32_16x16x32_bf16(a[ks], b[ks], acc, 0, 0, 0);
    float bb = bias[col];
    #pragma unroll
    for (int rr = 0; rr < 4; ++rr) {
      int row = wv * 16 + 4 * lg + rr;
      float y = acc[rr] * sr[rr] + bb;
      if (useCorr) y += corr[row * 128 + col];
      yreg[nt][rr] = y;
      ssq[rr] += y * y;
    }
  }
  float inv[4], sc[4];
  #pragma unroll
  for (int rr = 0; rr < 4; ++rr) {
    float ss = ssq[rr];
    ss += __shfl_xor(ss, 1); ss += __shfl_xor(ss, 2);
    ss += __shfl_xor(ss, 4); ss += __shfl_xor(ss, 8);
    inv[rr] = 1.0f / fmaxf(sqrtf(ss), 1e-12f);
  }
  float ss2[4] = {0.f, 0.f, 0.f, 0.f};
  #pragma unroll
  for (int nt = 0; nt < 8; ++nt)
    #pragma unroll
    for (int rr = 0; rr < 4; ++rr) {
      float v = fmaxf(yreg[nt][rr] * inv[rr], 0.f);
      yreg[nt][rr] = v;
      ss2[rr] += v * v;
    }
  #pragma unroll
  for (int rr = 0; rr < 4; ++rr) {
    float ss = ss2[rr];
    ss += __shfl_xor(ss, 1); ss += __shfl_xor(ss, 2);
    ss += __shfl_xor(ss, 4); ss += __shfl_xor(ss, 8);
    sc[rr] = sqrtf(128.0f / fmaxf(ss, 1e-20f));
  }
  #pragma unroll
  for (int nt = 0; nt < 8; ++nt)
    #pragma unroll
    for (int rr = 0; rr < 4; ++rr) {
      int row = wv * 16 + 4 * lg + rr;
      Fg[((size_t)blk * 64 + row) * 128 + nt * 16 + lr] = f2b(yreg[nt][rr] * sc[rr]);
    }
}

// ---------------- K2: fused SAGE, 512 blocks x 64 rows ----------------
__global__ __launch_bounds__(256, 2) void sage_fused(
    const float* __restrict__ flows, const ushort* __restrict__ WR,
    const float* __restrict__ bl1, const float* __restrict__ bl2,
    const float* __restrict__ bl3, const float* __restrict__ bl4,
    const float* __restrict__ C1, const float* __restrict__ C2,
    const float* __restrict__ C3, const float* __restrict__ C4,
    ushort* __restrict__ Fg) {
  __shared__ char Xt[32768];
  __shared__ float sA[64], sB[64];
  int blk = blockIdx.x, tid = threadIdx.x;
  int lane = tid & 63, wv = tid >> 6, lr = lane & 15, lg = lane >> 4;
  stage_flows64(flows, blk, Xt, sA, wv, lane);
  bool c = (blk < 2);
  int ro = c ? blk * 64 : 0;
  sage_layer_mid64<128, 128>(Xt, sA, sB, WR + 0,     bl1, C1 + ro * 128, c, wv, lr, lg);
  sage_layer_mid64<128, 256>(Xt, sB, sA, WR + 16384, bl2, C2 + ro * 256, c, wv, lr, lg);
  sage_layer_mid64<256, 128>(Xt, sA, sB, WR + 49152, bl3, C3 + ro * 128, c, wv, lr, lg);
  sage_layer_last64(Xt, sB, WR + 81920, bl4, C4 + ro * 128, c, wv, lr, lg, Fg, blk);
}

// ---------------- K1: batch-0 chain -> corr tables (128 rows, 1 block) ----------------
template <int K, int N, bool CORRONLY>
__device__ inline void chain_layer(char* Xt, char* C0T, const float* sP, float* sN,
                                   const ushort* __restrict__ Wl, const ushort* __restrict__ Wr,
                                   const float* __restrict__ bias, float* __restrict__ Cg,
                                   int wv, int lr, int lg) {
  __syncthreads();
  bf16x8 a[2][K / 32];
  float sr[2][4];
  #pragma unroll
  for (int m = 0; m < 2; ++m) {
    int rowA = wv * 32 + m * 16 + lr;
    #pragma unroll
    for (int ks = 0; ks < K / 32; ++ks)
      a[m][ks] = *reinterpret_cast<const bf16x8*>(
          Xt + rowA * (K * 2) + ((ks * 64 + lg * 16) ^ ((rowA & 7) << 4)));
    #pragma unroll
    for (int rr = 0; rr < 4; ++rr) sr[m][rr] = sP[wv * 32 + m * 16 + 4 * lg + rr];
  }
  __syncthreads();
  #pragma unroll
  for (int nt = 0; nt < N / 16; ++nt) {
    int col = nt * 16 + lr;
    bf16x8 b[K / 32];
    #pragma unroll
    for (int ks = 0; ks < K / 32; ++ks)
      b[ks] = *reinterpret_cast<const bf16x8*>(Wl + col * K + ks * 32 + lg * 8);
    f32x4 acc[2] = {{0.f, 0.f, 0.f, 0.f}, {0.f, 0.f, 0.f, 0.f}};
    #pragma unroll
    for (int ks = 0; ks < K / 32; ++ks) {
      acc[0] = __builtin_amdgcn_mfma_f32_16x16x32_bf16(a[0][ks], b[ks], acc[0], 0, 0, 0);
      acc[1] = __builtin_amdgcn_mfma_f32_16x16x32_bf16(a[1][ks], b[ks], acc[1], 0, 0, 0);
    }
    #pragma unroll
    for (int m = 0; m < 2; ++m)
      #pragma unroll
      for (int rr = 0; rr < 4; ++rr) {
        int row = wv * 32 + m * 16 + 4 * lg + rr;
        *reinterpret_cast<ushort*>(C0T + col * 256 + ((row * 2) ^ ((col & 7) << 4))) =
            f2b(acc[m][rr] * sr[m][rr]);
      }
  }
  __syncthreads();
  bf16x8 aL[2][4];
  #pragma unroll
  for (int m = 0; m < 2; ++m) {
    int rowL = wv * 32 + m * 16 + lr;
    ushort iv = f2b(1.0f / (float)(rowL > 1 ? rowL : 1));
    #pragma unroll
    for (int ks = 0; ks < 4; ++ks)
      #pragma unroll
      for (int j = 0; j < 8; ++j) {
        int k = ks * 32 + lg * 8 + j;
        aL[m][ks][j] = (short)((k < rowL) ? iv : 0);
      }
  }
  float ssq[2][4] = {{0.f, 0.f, 0.f, 0.f}, {0.f, 0.f, 0.f, 0.f}};
  #pragma unroll
  for (int nt = 0; nt < N / 16; ++nt) {
    int col = nt * 16 + lr;
    bf16x8 bc[4];
    #pragma unroll
    for (int ks = 0; ks < 4; ++ks)
      bc[ks] = *reinterpret_cast<const bf16x8*>(
          C0T + col * 256 + ((ks * 64 + lg * 16) ^ ((col & 7) << 4)));
    f32x4 cacc[2] = {{0.f, 0.f, 0.f, 0.f}, {0.f, 0.f, 0.f, 0.f}};
    #pragma unroll
    for (int ks = 0; ks < 4; ++ks) {
      cacc[0] = __builtin_amdgcn_mfma_f32_16x16x32_bf16(aL[0][ks], bc[ks], cacc[0], 0, 0, 0);
      cacc[1] = __builtin_amdgcn_mfma_f32_16x16x32_bf16(aL[1][ks], bc[ks], cacc[1], 0, 0, 0);
    }
    #pragma unroll
    for (int m = 0; m < 2; ++m)
      #pragma unroll
      for (int rr = 0; rr < 4; ++rr) {
        int row = wv * 32 + m * 16 + 4 * lg + rr;
        Cg[row * N + col] = cacc[m][rr];
      }
    if (!CORRONLY) {
      bf16x8 b[K / 32];
      #pragma unroll
      for (int ks = 0; ks < K / 32; ++ks)
        b[ks] = *reinterpret_cast<const bf16x8*>(Wr + col * K + ks * 32 + lg * 8);
      f32x4 acc[2] = {{0.f, 0.f, 0.f, 0.f}, {0.f, 0.f, 0.f, 0.f}};
      #pragma unroll
      for (int ks = 0; ks < K / 32; ++ks) {
        acc[0] = __builtin_amdgcn_mfma_f32_16x16x32_bf16(a[0][ks], b[ks], acc[0], 0, 0, 0);
        acc[1] = __builtin_amdgcn_mfma_f32_16x16x32_bf16(a[1][ks], b[ks], acc[1], 0, 0, 0);
      }
      float bb = bias[col];
      #pragma unroll
      for (int m = 0; m < 2; ++m)
        #pragma unroll
        for (int rr = 0; rr < 4; ++rr) {
          int row = wv * 32 + m * 16 + 4 * lg + rr;
          float y = acc[m][rr] * sr[m][rr] + bb + cacc[m][rr];
          *reinterpret_cast<ushort*>(Xt + row * (N * 2) + ((col * 2) ^ ((row & 7) << 4))) = f2b(y);
          ssq[m][rr] += y * y;
        }
    }
  }
  if (!CORRONLY) {
    #pragma unroll
    for (int m = 0; m < 2; ++m)
      #pragma unroll
      for (int rr = 0; rr < 4; ++rr) {
        float ss = ssq[m][rr];
        ss += __shfl_xor(ss, 1); ss += __shfl_xor(ss, 2);
        ss += __shfl_xor(ss, 4); ss += __shfl_xor(ss, 8);
        if (lr == 0) sN[wv * 32 + m * 16 + 4 * lg + rr] = 1.0f / fmaxf(sqrtf(ss), 1e-12f);
      }
  }
}

__global__ __launch_bounds__(256, 1) void chain0_k(
    const float* __restrict__ flows, const ushort* __restrict__ WL, const ushort* __restrict__ WR,
    const float* __restrict__ bl1, const float* __restrict__ bl2, const float* __restrict__ bl3,
    float* __restrict__ C1, float* __restrict__ C2, float* __restrict__ C3, float* __restrict__ C4) {
  __shared__ char Xt[65536];
  __shared__ char C0T[65536];
  __shared__ float sA[128], sB[128];
  int tid = threadIdx.x;
  int lane = tid & 63, wv = tid >> 6, lr = lane & 15, lg = lane >> 4;
  stage_flows128(flows, 0, Xt, sA, wv, lane);
  chain_layer<128, 128, false>(Xt, C0T, sA, sB, WL + 0,     WR + 0,     bl1, C1, wv, lr, lg);
  chain_layer<128, 256, false>(Xt, C0T, sB, sA, WL + 16384, WR + 16384, bl2, C2, wv, lr, lg);
  chain_layer<256, 128, false>(Xt, C0T, sA, sB, WL + 49152, WR + 49152, bl3, C3, wv, lr, lg);
  chain_layer<128, 128, true >(Xt, C0T, sB, sA, WL + 81920, WR + 81920, nullptr, C4, wv, lr, lg);
}

// ---------------- fused attention (M-route, F in LDS): 512 blocks = 256 batches x 2 halves ----------------
// Per block: stage full F[b] (128x128 bf16, 32 KB) into LDS once; 8 waves (4 row x 2 col).
// Per worker w: A: G=f@MB_w -> Gl; bar; B: P=G@F^T (F from LDS) -> Pl; bar; C: out += P@SB_w^T.
__global__ __launch_bounds__(512, 2) void attn_fused(
    const ushort* __restrict__ F, const ushort* __restrict__ MB,
    const ushort* __restrict__ SB, float* __restrict__ Out) {
  __shared__ char Fl[32768];
  __shared__ char Gl[16384];
  __shared__ char Pl[16384];

  const int bh = blockIdx.x;
  const int b = bh >> 1, half = bh & 1;
  const int tid = threadIdx.x;
  const int l = tid & 63, wv = tid >> 6;
  const int wr = wv >> 1, wc = wv & 1;
  const int lr = l & 15, lg = l >> 4;

  const ushort* Fb = F + (size_t)b * 16384;

  // stage F tile: rows of 256 B, XOR-swizzled in 16B units (matches all reads below)
  for (int e = tid; e < 2048; e += 512) {
    int r = e >> 4, c = e & 15;
    uint4 v = *reinterpret_cast<const uint4*>(Fb + r * 128 + c * 8);
    *reinterpret_cast<uint4*>(Fl + r * 256 + ((c * 16) ^ ((r & 7) << 4))) = v;
  }
  __syncthreads();

  const int nG = half * 64 + wr * 16;   // wave's global row-tile base
  const int nr = wr * 16 + lr;          // local A-frag row in Gl/Pl (0..63)
  const int nFa = nG + lr;              // F row for the A-fragment

  // f A-fragments for this wave's 16 rows (persist across workers)
  bf16x8 fa[4];
  #pragma unroll
  for (int ks = 0; ks < 4; ++ks)
    fa[ks] = *reinterpret_cast<const bf16x8*>(
        Fl + nFa * 256 + ((ks * 64 + lg * 16) ^ ((nFa & 7) << 4)));

  f32x4 oacc[4];
  #pragma unroll
  for (int j = 0; j < 4; ++j) oacc[j] = f32x4{0.f, 0.f, 0.f, 0.f};

  for (int w = 0; w < 8; ++w) {
    const ushort* mb = MB + w * 16384;
    const ushort* sb = SB + w * 16384;

    // ---- Phase A: G[n][o] = f @ MB_w, o in wave's 64-col half ----
    #pragma unroll
    for (int j = 0; j < 4; ++j) {
      int o = wc * 64 + j * 16 + lr;
      bf16x8 bm[4];
      #pragma unroll
      for (int ks = 0; ks < 4; ++ks)
        bm[ks] = *reinterpret_cast<const bf16x8*>(mb + o * 128 + ks * 32 + lg * 8);
      f32x4 g = {0.f, 0.f, 0.f, 0.f};
      #pragma unroll
      for (int ks = 0; ks < 4; ++ks)
        g = __builtin_amdgcn_mfma_f32_16x16x32_bf16(fa[ks], bm[ks], g, 0, 0, 0);
      int nb = wr * 16 + lg * 4;
      #pragma unroll
      for (int r = 0; r < 4; ++r) {
        int n = nb + r;
        *reinterpret_cast<ushort*>(Gl + n * 256 + ((o * 2) ^ ((n & 7) << 4))) = f2b(g[r]);
      }
    }
    __syncthreads();

    // ---- Phase B: P[n][m] = G @ F^T (F rows m from LDS) ----
    bf16x8 ga[4];
    #pragma unroll
    for (int ks = 0; ks < 4; ++ks)
      ga[ks] = *reinterpret_cast<const bf16x8*>(Gl + nr * 256 + ((ks * 64 + lg * 16) ^ ((nr & 7) << 4)));
    #pragma unroll
    for (int j = 0; j < 4; ++j) {
      int m = wc * 64 + j * 16 + lr;
      bf16x8 bf_[4];
      #pragma unroll
      for (int ks = 0; ks < 4; ++ks)
        bf_[ks] = *reinterpret_cast<const bf16x8*>(
            Fl + m * 256 + ((ks * 64 + lg * 16) ^ ((m & 7) << 4)));
      f32x4 p = {0.f, 0.f, 0.f, 0.f};
      #pragma unroll
      for (int ks = 0; ks < 4; ++ks)
        p = __builtin_amdgcn_mfma_f32_16x16x32_bf16(ga[ks], bf_[ks], p, 0, 0, 0);
      int nb = wr * 16 + lg * 4;
      #pragma unroll
      for (int r = 0; r < 4; ++r) {
        int n = nb + r;
        *reinterpret_cast<ushort*>(Pl + n * 256 + ((m * 2) ^ ((n & 7) << 4))) = f2b(p[r]);
      }
    }
    __syncthreads();

    // ---- Phase C: out += P @ SB_w^T, p-cols in wave's half ----
    // (no trailing barrier: next A writes Gl which nobody reads now; the post-A
    //  barrier of w+1 orders C's Pl reads before B_{w+1}'s Pl writes)
    bf16x8 pa[4];
    #pragma unroll
    for (int ks = 0; ks < 4; ++ks)
      pa[ks] = *reinterpret_cast<const bf16x8*>(Pl + nr * 256 + ((ks * 64 + lg * 16) ^ ((nr & 7) << 4)));
    #pragma unroll
    for (int j = 0; j < 4; ++j) {
      int p = wc * 64 + j * 16 + lr;
      bf16x8 bs[4];
      #pragma unroll
      for (int ks = 0; ks < 4; ++ks)
        bs[ks] = *reinterpret_cast<const bf16x8*>(sb + p * 128 + ks * 32 + lg * 8);
      #pragma unroll
      for (int ks = 0; ks < 4; ++ks)
        oacc[j] = __builtin_amdgcn_mfma_f32_16x16x32_bf16(pa[ks], bs[ks], oacc[j], 0, 0, 0);
    }
  }

  const float inv_scale = 0.08838834764831845f;
  float* ob = Out + (size_t)b * 16384;
  #pragma unroll
  for (int j = 0; j < 4; ++j) {
    int p = wc * 64 + j * 16 + lr;
    #pragma unroll
    for (int r = 0; r < 4; ++r)
      ob[(nG + lg * 4 + r) * 128 + p] = oacc[j][r] * inv_scale;
  }
}

extern "C" void kernel_launch(void* const* d_in, const int* in_sizes, int n_in,
                              void* d_out, int out_size, void* d_ws, size_t ws_size,
                              hipStream_t stream) {
  const float* flows = (const float*)d_in[0];
  const float* g1_wl = (const float*)d_in[10];
  const float* g1_bl = (const float*)d_in[11];
  const float* g1_wr = (const float*)d_in[12];
  const float* g2_wl = (const float*)d_in[13];
  const float* g2_bl = (const float*)d_in[14];
  const float* g2_wr = (const float*)d_in[15];
  const float* g3_wl = (const float*)d_in[16];
  const float* g3_bl = (const float*)d_in[17];
  const float* g3_wr = (const float*)d_in[18];
  const float* g4_wl = (const float*)d_in[19];
  const float* g4_bl = (const float*)d_in[20];
  const float* g4_wr = (const float*)d_in[21];
  const float* qsa   = (const float*)d_in[24];
  const float* ksa   = (const float*)d_in[25];
  const float* s2w   = (const float*)d_in[27];
  float* out = (float*)d_out;
  char* wsb  = (char*)d_ws;

  // workspace layout (bytes)
  ushort* FB16 = (ushort*)(wsb);                 // 32768*128 bf16 = 8388608
  ushort* SB   = (ushort*)(wsb + 8388608);       // 131072 bf16 = 262144
  ushort* WL   = (ushort*)(wsb + 8650752);       // 98304 bf16 = 196608
  ushort* WR   = (ushort*)(wsb + 8847360);       // 196608
  ushort* MBws = (ushort*)(wsb + 9043968);       // 131072 bf16 = 262144
  float*  C1   = (float*)(wsb + 9306112);        // 128*128 f32
  float*  C2   = (float*)(wsb + 9371648);        // 128*256 f32
  float*  C3   = (float*)(wsb + 9502720);
  float*  C4   = (float*)(wsb + 9568256);

  prep_all_k<<<896, 256, 0, stream>>>(s2w,
                                      g1_wl, g2_wl, g3_wl, g4_wl,
                                      g1_wr, g2_wr, g3_wr, g4_wr,
                                      SB, WL, WR);
  prep_mb_k<<<8, 256, 0, stream>>>(qsa, ksa, MBws);
  chain0_k<<<1, 256, 0, stream>>>(flows, WL, WR, g1_bl, g2_bl, g3_bl, C1, C2, C3, C4);
  sage_fused<<<512, 256, 0, stream>>>(flows, WR, g1_bl, g2_bl, g3_bl, g4_bl,
                                      C1, C2, C3, C4, FB16);
  attn_fused<<<512, 512, 0, stream>>>(FB16, MBws, SB, out);
}

// Round 13
// 285.253 us; speedup vs baseline: 1.2069x; 1.1181x over previous
//
#include <hip/hip_runtime.h>
#include <math.h>

// Model_6150393168181 — fully bf16-MFMA pipeline.
// out[b] = (1/sqrt(128)) * sum_w (f qsa_w^T) (S_w f ksa_w^T)^T
//   MB_w[o][d] = sum_{o'} ksa[w,o',o] qsa[w,o',d]   (precomputed, bf16)
//   G_w = f MB_w^T   P_w = G_w f^T   out += P_w SB_w^T
// attn: 1024 blocks = 256 batches x 4 row-quarters (32 rows), 4 waves, 48 KB LDS,
// 3 blocks/CU. Orientation chosen so every LDS intermediate write is a packed
// uint2 (D-frag's 4 consecutive rows land contiguously) and every read is b128.
// f = rms(relu(SAGE4(rms(flows)))); SAGE agg via corr_l = L @ (X_l @ wl_l^T) (chain0_k).

typedef __attribute__((ext_vector_type(8))) short bf16x8;
typedef __attribute__((ext_vector_type(4))) float f32x4;

__device__ inline ushort f2b(float x) {
  unsigned u = __builtin_bit_cast(unsigned, x);
  unsigned r = (u + 0x7fffu + ((u >> 16) & 1u)) >> 16;
  return (ushort)r;
}

// ---------------- prep: SB reorder + SAGE weight conversions ----------------
__global__ __launch_bounds__(256) void prep_all_k(
    const float* __restrict__ s2w,
    const float* __restrict__ wl1, const float* __restrict__ wl2,
    const float* __restrict__ wl3, const float* __restrict__ wl4,
    const float* __restrict__ wr1, const float* __restrict__ wr2,
    const float* __restrict__ wr3, const float* __restrict__ wr4,
    ushort* __restrict__ SB, ushort* __restrict__ WL, ushort* __restrict__ WR) {
  int i = blockIdx.x * 256 + threadIdx.x;
  if (i < 131072) {
    int w = i >> 14, p = (i >> 7) & 127, m = i & 127;
    SB[i] = f2b(s2w[p * 1024 + m * 8 + w]);
    return;
  }
  i -= 131072;
  if (i < 98304) {
    float v, u;
    if      (i < 16384) { v = wl1[i];         u = wr1[i]; }
    else if (i < 49152) { v = wl2[i - 16384]; u = wr2[i - 16384]; }
    else if (i < 81920) { v = wl3[i - 49152]; u = wr3[i - 49152]; }
    else                { v = wl4[i - 81920]; u = wr4[i - 81920]; }
    WL[i] = f2b(v);
    WR[i] = f2b(u);
  }
}

// ---------------- prep: MB_w[o][d] = sum_{o'} ksa[w,o',o] * qsa[w,o',d] ----------------
__global__ __launch_bounds__(256, 1) void prep_mb_k(
    const float* __restrict__ qsa, const float* __restrict__ ksa,
    ushort* __restrict__ MB) {
  __shared__ char QT[32768];   // QT[d][o'] = qsa[w][o'][d]
  __shared__ char KTm[32768];  // KTm[o][o'] = ksa[w][o'][o]
  int w = blockIdx.x, tid = threadIdx.x;
  const float* qw = qsa + (size_t)w * 16384;
  const float* kw = ksa + (size_t)w * 16384;
  for (int e = tid; e < 16384; e += 256) {
    int op = e >> 7, c = e & 127;
    int off = c * 256 + ((op * 2) ^ ((c & 7) << 4));
    *reinterpret_cast<ushort*>(QT + off)  = f2b(qw[e]);
    *reinterpret_cast<ushort*>(KTm + off) = f2b(kw[e]);
  }
  __syncthreads();
  int l = tid & 63, wv = tid >> 6, lr = l & 15, lg = l >> 4;
  #pragma unroll
  for (int rt = 0; rt < 2; ++rt) {
    int o = wv * 32 + rt * 16 + lr;
    bf16x8 a[4];
    #pragma unroll
    for (int ks = 0; ks < 4; ++ks)
      a[ks] = *reinterpret_cast<const bf16x8*>(KTm + o * 256 + ((ks * 64 + lg * 16) ^ ((o & 7) << 4)));
    #pragma unroll
    for (int ct = 0; ct < 8; ++ct) {
      int d = ct * 16 + lr;
      bf16x8 bq[4];
      #pragma unroll
      for (int ks = 0; ks < 4; ++ks)
        bq[ks] = *reinterpret_cast<const bf16x8*>(QT + d * 256 + ((ks * 64 + lg * 16) ^ ((d & 7) << 4)));
      f32x4 acc = {0.f, 0.f, 0.f, 0.f};
      #pragma unroll
      for (int ks = 0; ks < 4; ++ks)
        acc = __builtin_amdgcn_mfma_f32_16x16x32_bf16(a[ks], bq[ks], acc, 0, 0, 0);
      #pragma unroll
      for (int r = 0; r < 4; ++r)
        MB[(size_t)w * 16384 + (wv * 32 + rt * 16 + lg * 4 + r) * 128 + ct * 16 + lr] = f2b(acc[r]);
    }
  }
}

// ---------------- stage 128 rows (chain0 only): raw bf16 + rms scale ----------------
__device__ inline void stage_flows128(const float* __restrict__ flows, int blk,
                                      char* Xt, float* sArr, int wv, int lane) {
  for (int r = 0; r < 32; ++r) {
    int row = wv * 32 + r;
    const float2 v = *reinterpret_cast<const float2*>(
        flows + ((size_t)blk * 128 + row) * 128 + lane * 2);
    float ss = v.x * v.x + v.y * v.y;
    ss += __shfl_xor(ss, 32); ss += __shfl_xor(ss, 16); ss += __shfl_xor(ss, 8);
    ss += __shfl_xor(ss, 4);  ss += __shfl_xor(ss, 2);  ss += __shfl_xor(ss, 1);
    unsigned pk = (unsigned)f2b(v.x) | ((unsigned)f2b(v.y) << 16);
    *reinterpret_cast<unsigned*>(Xt + row * 256 + ((lane * 4) ^ ((row & 7) << 4))) = pk;
    if (lane == 0) sArr[row] = rsqrtf(ss * (1.0f / 128.0f));
  }
}

// ---------------- stage 64 rows (sage_fused): 8 unrolled float4 loads per wave ----------------
__device__ inline void stage_flows64(const float* __restrict__ flows, int blk,
                                     char* Xt, float* sArr, int wv, int lane) {
  int r2 = lane >> 5;
  int c4 = lane & 31;
  #pragma unroll
  for (int it = 0; it < 8; ++it) {
    int rowbase = wv * 16 + it * 2;
    const float4 v = *reinterpret_cast<const float4*>(
        flows + ((size_t)blk * 64 + rowbase) * 128 + lane * 4);
    int row = rowbase + r2;
    float ss = v.x * v.x + v.y * v.y + v.z * v.z + v.w * v.w;
    ss += __shfl_xor(ss, 16); ss += __shfl_xor(ss, 8);
    ss += __shfl_xor(ss, 4);  ss += __shfl_xor(ss, 2); ss += __shfl_xor(ss, 1);
    uint2 pk;
    pk.x = (unsigned)f2b(v.x) | ((unsigned)f2b(v.y) << 16);
    pk.y = (unsigned)f2b(v.z) | ((unsigned)f2b(v.w) << 16);
    *reinterpret_cast<uint2*>(Xt + row * 256 + ((c4 * 8) ^ ((row & 7) << 4))) = pk;
    if (c4 == 0) sArr[row] = rsqrtf(ss * (1.0f / 128.0f));
  }
}

// ---------------- mid SAGE layer (64-row block) ----------------
template <int K, int N>
__device__ inline void sage_layer_mid64(char* Xt, const float* sP, float* sN,
                                        const ushort* __restrict__ Wr,
                                        const float* __restrict__ bias,
                                        const float* __restrict__ corr, bool useCorr,
                                        int wv, int lr, int lg) {
  __syncthreads();
  bf16x8 a[K / 32];
  float sr[4];
  int rowA = wv * 16 + lr;
  #pragma unroll
  for (int ks = 0; ks < K / 32; ++ks)
    a[ks] = *reinterpret_cast<const bf16x8*>(
        Xt + rowA * (K * 2) + ((ks * 64 + lg * 16) ^ ((rowA & 7) << 4)));
  #pragma unroll
  for (int rr = 0; rr < 4; ++rr) sr[rr] = sP[wv * 16 + 4 * lg + rr];
  __syncthreads();
  float ssq[4] = {0.f, 0.f, 0.f, 0.f};
  #pragma unroll
  for (int nt = 0; nt < N / 16; ++nt) {
    int col = nt * 16 + lr;
    bf16x8 b[K / 32];
    #pragma unroll
    for (int ks = 0; ks < K / 32; ++ks)
      b[ks] = *reinterpret_cast<const bf16x8*>(Wr + col * K + ks * 32 + lg * 8);
    f32x4 acc = {0.f, 0.f, 0.f, 0.f};
    #pragma unroll
    for (int ks = 0; ks < K / 32; ++ks)
      acc = __builtin_amdgcn_mfma_f32_16x16x32_bf16(a[ks], b[ks], acc, 0, 0, 0);
    float bb = bias[col];
    #pragma unroll
    for (int rr = 0; rr < 4; ++rr) {
      int row = wv * 16 + 4 * lg + rr;
      float y = acc[rr] * sr[rr] + bb;
      if (useCorr) y += corr[row * N + col];
      *reinterpret_cast<ushort*>(Xt + row * (N * 2) + ((col * 2) ^ ((row & 7) << 4))) = f2b(y);
      ssq[rr] += y * y;
    }
  }
  #pragma unroll
  for (int rr = 0; rr < 4; ++rr) {
    float ss = ssq[rr];
    ss += __shfl_xor(ss, 1); ss += __shfl_xor(ss, 2);
    ss += __shfl_xor(ss, 4); ss += __shfl_xor(ss, 8);
    if (lr == 0) sN[wv * 16 + 4 * lg + rr] = 1.0f / fmaxf(sqrtf(ss), 1e-12f);
  }
}

// ---------------- last SAGE layer (64-row block) ----------------
__device__ inline void sage_layer_last64(char* Xt, const float* sP,
                                         const ushort* __restrict__ Wr,
                                         const float* __restrict__ bias,
                                         const float* __restrict__ corr, bool useCorr,
                                         int wv, int lr, int lg,
                                         ushort* __restrict__ Fg, int blk) {
  __syncthreads();
  bf16x8 a[4];
  float sr[4];
  int rowA = wv * 16 + lr;
  #pragma unroll
  for (int ks = 0; ks < 4; ++ks)
    a[ks] = *reinterpret_cast<const bf16x8*>(
        Xt + rowA * 256 + ((ks * 64 + lg * 16) ^ ((rowA & 7) << 4)));
  #pragma unroll
  for (int rr = 0; rr < 4; ++rr) sr[rr] = sP[wv * 16 + 4 * lg + rr];
  __syncthreads();
  float yreg[8][4];
  float ssq[4] = {0.f, 0.f, 0.f, 0.f};
  #pragma unroll
  for (int nt = 0; nt < 8; ++nt) {
    int col = nt * 16 + lr;
    bf16x8 b[4];
    #pragma unroll
    for (int ks = 0; ks < 4; ++ks)
      b[ks] = *reinterpret_cast<const bf16x8*>(Wr + col * 128 + ks * 32 + lg * 8);
    f32x4 acc = {0.f, 0.f, 0.f, 0.f};
    #pragma unroll
    for (int ks = 0; ks < 4; ++ks)
      acc = __builtin_amdgcn_mfma_f32_16x16x32_bf16(a[ks], b[ks], acc, 0, 0, 0);
    float bb = bias[col];
    #pragma unroll
    for (int rr = 0; rr < 4; ++rr) {
      int row = wv * 16 + 4 * lg + rr;
      float y = acc[rr] * sr[rr] + bb;
      if (useCorr) y += corr[row * 128 + col];
      yreg[nt][rr] = y;
      ssq[rr] += y * y;
    }
  }
  float inv[4], sc[4];
  #pragma unroll
  for (int rr = 0; rr < 4; ++rr) {
    float ss = ssq[rr];
    ss += __shfl_xor(ss, 1); ss += __shfl_xor(ss, 2);
    ss += __shfl_xor(ss, 4); ss += __shfl_xor(ss, 8);
    inv[rr] = 1.0f / fmaxf(sqrtf(ss), 1e-12f);
  }
  float ss2[4] = {0.f, 0.f, 0.f, 0.f};
  #pragma unroll
  for (int nt = 0; nt < 8; ++nt)
    #pragma unroll
    for (int rr = 0; rr < 4; ++rr) {
      float v = fmaxf(yreg[nt][rr] * inv[rr], 0.f);
      yreg[nt][rr] = v;
      ss2[rr] += v * v;
    }
  #pragma unroll
  for (int rr = 0; rr < 4; ++rr) {
    float ss = ss2[rr];
    ss += __shfl_xor(ss, 1); ss += __shfl_xor(ss, 2);
    ss += __shfl_xor(ss, 4); ss += __shfl_xor(ss, 8);
    sc[rr] = sqrtf(128.0f / fmaxf(ss, 1e-20f));
  }
  #pragma unroll
  for (int nt = 0; nt < 8; ++nt)
    #pragma unroll
    for (int rr = 0; rr < 4; ++rr) {
      int row = wv * 16 + 4 * lg + rr;
      Fg[((size_t)blk * 64 + row) * 128 + nt * 16 + lr] = f2b(yreg[nt][rr] * sc[rr]);
    }
}

// ---------------- K2: fused SAGE, 512 blocks x 64 rows ----------------
__global__ __launch_bounds__(256, 2) void sage_fused(
    const float* __restrict__ flows, const ushort* __restrict__ WR,
    const float* __restrict__ bl1, const float* __restrict__ bl2,
    const float* __restrict__ bl3, const float* __restrict__ bl4,
    const float* __restrict__ C1, const float* __restrict__ C2,
    const float* __restrict__ C3, const float* __restrict__ C4,
    ushort* __restrict__ Fg) {
  __shared__ char Xt[32768];
  __shared__ float sA[64], sB[64];
  int blk = blockIdx.x, tid = threadIdx.x;
  int lane = tid & 63, wv = tid >> 6, lr = lane & 15, lg = lane >> 4;
  stage_flows64(flows, blk, Xt, sA, wv, lane);
  bool c = (blk < 2);
  int ro = c ? blk * 64 : 0;
  sage_layer_mid64<128, 128>(Xt, sA, sB, WR + 0,     bl1, C1 + ro * 128, c, wv, lr, lg);
  sage_layer_mid64<128, 256>(Xt, sB, sA, WR + 16384, bl2, C2 + ro * 256, c, wv, lr, lg);
  sage_layer_mid64<256, 128>(Xt, sA, sB, WR + 49152, bl3, C3 + ro * 128, c, wv, lr, lg);
  sage_layer_last64(Xt, sB, WR + 81920, bl4, C4 + ro * 128, c, wv, lr, lg, Fg, blk);
}

// ---------------- K1: batch-0 chain -> corr tables (128 rows, 1 block) ----------------
template <int K, int N, bool CORRONLY>
__device__ inline void chain_layer(char* Xt, char* C0T, const float* sP, float* sN,
                                   const ushort* __restrict__ Wl, const ushort* __restrict__ Wr,
                                   const float* __restrict__ bias, float* __restrict__ Cg,
                                   int wv, int lr, int lg) {
  __syncthreads();
  bf16x8 a[2][K / 32];
  float sr[2][4];
  #pragma unroll
  for (int m = 0; m < 2; ++m) {
    int rowA = wv * 32 + m * 16 + lr;
    #pragma unroll
    for (int ks = 0; ks < K / 32; ++ks)
      a[m][ks] = *reinterpret_cast<const bf16x8*>(
          Xt + rowA * (K * 2) + ((ks * 64 + lg * 16) ^ ((rowA & 7) << 4)));
    #pragma unroll
    for (int rr = 0; rr < 4; ++rr) sr[m][rr] = sP[wv * 32 + m * 16 + 4 * lg + rr];
  }
  __syncthreads();
  #pragma unroll
  for (int nt = 0; nt < N / 16; ++nt) {
    int col = nt * 16 + lr;
    bf16x8 b[K / 32];
    #pragma unroll
    for (int ks = 0; ks < K / 32; ++ks)
      b[ks] = *reinterpret_cast<const bf16x8*>(Wl + col * K + ks * 32 + lg * 8);
    f32x4 acc[2] = {{0.f, 0.f, 0.f, 0.f}, {0.f, 0.f, 0.f, 0.f}};
    #pragma unroll
    for (int ks = 0; ks < K / 32; ++ks) {
      acc[0] = __builtin_amdgcn_mfma_f32_16x16x32_bf16(a[0][ks], b[ks], acc[0], 0, 0, 0);
      acc[1] = __builtin_amdgcn_mfma_f32_16x16x32_bf16(a[1][ks], b[ks], acc[1], 0, 0, 0);
    }
    #pragma unroll
    for (int m = 0; m < 2; ++m)
      #pragma unroll
      for (int rr = 0; rr < 4; ++rr) {
        int row = wv * 32 + m * 16 + 4 * lg + rr;
        *reinterpret_cast<ushort*>(C0T + col * 256 + ((row * 2) ^ ((col & 7) << 4))) =
            f2b(acc[m][rr] * sr[m][rr]);
      }
  }
  __syncthreads();
  bf16x8 aL[2][4];
  #pragma unroll
  for (int m = 0; m < 2; ++m) {
    int rowL = wv * 32 + m * 16 + lr;
    ushort iv = f2b(1.0f / (float)(rowL > 1 ? rowL : 1));
    #pragma unroll
    for (int ks = 0; ks < 4; ++ks)
      #pragma unroll
      for (int j = 0; j < 8; ++j) {
        int k = ks * 32 + lg * 8 + j;
        aL[m][ks][j] = (short)((k < rowL) ? iv : 0);
      }
  }
  float ssq[2][4] = {{0.f, 0.f, 0.f, 0.f}, {0.f, 0.f, 0.f, 0.f}};
  #pragma unroll
  for (int nt = 0; nt < N / 16; ++nt) {
    int col = nt * 16 + lr;
    bf16x8 bc[4];
    #pragma unroll
    for (int ks = 0; ks < 4; ++ks)
      bc[ks] = *reinterpret_cast<const bf16x8*>(
          C0T + col * 256 + ((ks * 64 + lg * 16) ^ ((col & 7) << 4)));
    f32x4 cacc[2] = {{0.f, 0.f, 0.f, 0.f}, {0.f, 0.f, 0.f, 0.f}};
    #pragma unroll
    for (int ks = 0; ks < 4; ++ks) {
      cacc[0] = __builtin_amdgcn_mfma_f32_16x16x32_bf16(aL[0][ks], bc[ks], cacc[0], 0, 0, 0);
      cacc[1] = __builtin_amdgcn_mfma_f32_16x16x32_bf16(aL[1][ks], bc[ks], cacc[1], 0, 0, 0);
    }
    #pragma unroll
    for (int m = 0; m < 2; ++m)
      #pragma unroll
      for (int rr = 0; rr < 4; ++rr) {
        int row = wv * 32 + m * 16 + 4 * lg + rr;
        Cg[row * N + col] = cacc[m][rr];
      }
    if (!CORRONLY) {
      bf16x8 b[K / 32];
      #pragma unroll
      for (int ks = 0; ks < K / 32; ++ks)
        b[ks] = *reinterpret_cast<const bf16x8*>(Wr + col * K + ks * 32 + lg * 8);
      f32x4 acc[2] = {{0.f, 0.f, 0.f, 0.f}, {0.f, 0.f, 0.f, 0.f}};
      #pragma unroll
      for (int ks = 0; ks < K / 32; ++ks) {
        acc[0] = __builtin_amdgcn_mfma_f32_16x16x32_bf16(a[0][ks], b[ks], acc[0], 0, 0, 0);
        acc[1] = __builtin_amdgcn_mfma_f32_16x16x32_bf16(a[1][ks], b[ks], acc[1], 0, 0, 0);
      }
      float bb = bias[col];
      #pragma unroll
      for (int m = 0; m < 2; ++m)
        #pragma unroll
        for (int rr = 0; rr < 4; ++rr) {
          int row = wv * 32 + m * 16 + 4 * lg + rr;
          float y = acc[m][rr] * sr[m][rr] + bb + cacc[m][rr];
          *reinterpret_cast<ushort*>(Xt + row * (N * 2) + ((col * 2) ^ ((row & 7) << 4))) = f2b(y);
          ssq[m][rr] += y * y;
        }
    }
  }
  if (!CORRONLY) {
    #pragma unroll
    for (int m = 0; m < 2; ++m)
      #pragma unroll
      for (int rr = 0; rr < 4; ++rr) {
        float ss = ssq[m][rr];
        ss += __shfl_xor(ss, 1); ss += __shfl_xor(ss, 2);
        ss += __shfl_xor(ss, 4); ss += __shfl_xor(ss, 8);
        if (lr == 0) sN[wv * 32 + m * 16 + 4 * lg + rr] = 1.0f / fmaxf(sqrtf(ss), 1e-12f);
      }
  }
}

__global__ __launch_bounds__(256, 1) void chain0_k(
    const float* __restrict__ flows, const ushort* __restrict__ WL, const ushort* __restrict__ WR,
    const float* __restrict__ bl1, const float* __restrict__ bl2, const float* __restrict__ bl3,
    float* __restrict__ C1, float* __restrict__ C2, float* __restrict__ C3, float* __restrict__ C4) {
  __shared__ char Xt[65536];
  __shared__ char C0T[65536];
  __shared__ float sA[128], sB[128];
  int tid = threadIdx.x;
  int lane = tid & 63, wv = tid >> 6, lr = lane & 15, lg = lane >> 4;
  stage_flows128(flows, 0, Xt, sA, wv, lane);
  chain_layer<128, 128, false>(Xt, C0T, sA, sB, WL + 0,     WR + 0,     bl1, C1, wv, lr, lg);
  chain_layer<128, 256, false>(Xt, C0T, sB, sA, WL + 16384, WR + 16384, bl2, C2, wv, lr, lg);
  chain_layer<256, 128, false>(Xt, C0T, sA, sB, WL + 49152, WR + 49152, bl3, C3, wv, lr, lg);
  chain_layer<128, 128, true >(Xt, C0T, sB, sA, WL + 81920, WR + 81920, nullptr, C4, wv, lr, lg);
}

// ---------------- fused attention v3: 1024 blocks = 256 b x 4 quarters, 4 waves ----------------
// Per worker w (all packed-write / b128-read):
//  A: D[o][n] = mfma(A=MB_w rows o, B=f rows n)  -> Gl[n][o]  (uint2 along o)
//  B: D[m][n] = mfma(A=f rows m,   B=Gl rows n)  -> Pl[n][m]  (uint2 along m)
//  C: D[n][p] = mfma(A=Pl rows n,  B=SB rows p)  -> oacc
__global__ __launch_bounds__(256, 3) void attn_fused(
    const ushort* __restrict__ F, const ushort* __restrict__ MB,
    const ushort* __restrict__ SB, float* __restrict__ Out) {
  __shared__ char Fl[32768];
  __shared__ char Gl[8192];
  __shared__ char Pl[8192];

  const int bq = blockIdx.x;
  const int b = bq >> 2, q = bq & 3;
  const int tid = threadIdx.x;
  const int l = tid & 63, wv = tid >> 6;
  const int lr = l & 15, lg = l >> 4;

  const ushort* Fb = F + (size_t)b * 16384;

  // stage full f (128 rows, swizzled 16B units)
  for (int e = tid; e < 2048; e += 256) {
    int r = e >> 4, c = e & 15;
    uint4 v = *reinterpret_cast<const uint4*>(Fb + r * 128 + c * 8);
    *reinterpret_cast<uint4*>(Fl + r * 256 + ((c * 16) ^ ((r & 7) << 4))) = v;
  }
  __syncthreads();

  // hoisted phase-A B-frags: f rows n = q*32 + nt*16 + lr (invariant over workers)
  bf16x8 bfn[2][4];
  #pragma unroll
  for (int nt = 0; nt < 2; ++nt) {
    int n = q * 32 + nt * 16 + lr;
    #pragma unroll
    for (int ks = 0; ks < 4; ++ks)
      bfn[nt][ks] = *reinterpret_cast<const bf16x8*>(
          Fl + n * 256 + ((ks * 64 + lg * 16) ^ ((n & 7) << 4)));
  }

  f32x4 oacc[2][2];
  #pragma unroll
  for (int nt = 0; nt < 2; ++nt)
    #pragma unroll
    for (int j = 0; j < 2; ++j) oacc[nt][j] = f32x4{0.f, 0.f, 0.f, 0.f};

  for (int w = 0; w < 8; ++w) {
    const ushort* mb = MB + w * 16384;
    const ushort* sb = SB + w * 16384;

    // ---- Phase A: Gl[n][o] ----
    #pragma unroll
    for (int j = 0; j < 2; ++j) {
      int o = (wv * 2 + j) * 16 + lr;
      bf16x8 am[4];
      #pragma unroll
      for (int ks = 0; ks < 4; ++ks)
        am[ks] = *reinterpret_cast<const bf16x8*>(mb + o * 128 + ks * 32 + lg * 8);
      #pragma unroll
      for (int nt = 0; nt < 2; ++nt) {
        f32x4 g = {0.f, 0.f, 0.f, 0.f};
        #pragma unroll
        for (int ks = 0; ks < 4; ++ks)
          g = __builtin_amdgcn_mfma_f32_16x16x32_bf16(am[ks], bfn[nt][ks], g, 0, 0, 0);
        // D[o][n]: 4 consecutive o = (wv*2+j)*16 + lg*4 + r, fixed n_local = nt*16 + lr
        int nl = nt * 16 + lr;
        int ob0 = 2 * ((wv * 2 + j) * 16 + lg * 4);
        uint2 pk;
        pk.x = (unsigned)f2b(g[0]) | ((unsigned)f2b(g[1]) << 16);
        pk.y = (unsigned)f2b(g[2]) | ((unsigned)f2b(g[3]) << 16);
        *reinterpret_cast<uint2*>(Gl + nl * 256 + (ob0 ^ ((nl & 7) << 4))) = pk;
      }
    }
    __syncthreads();

    // ---- Phase B: Pl[n][m] = mfma(A=f rows m, B=Gl rows n) ----
    #pragma unroll
    for (int j = 0; j < 2; ++j) {
      int m = (wv * 2 + j) * 16 + lr;
      bf16x8 af[4];
      #pragma unroll
      for (int ks = 0; ks < 4; ++ks)
        af[ks] = *reinterpret_cast<const bf16x8*>(
            Fl + m * 256 + ((ks * 64 + lg * 16) ^ ((m & 7) << 4)));
      #pragma unroll
      for (int nt = 0; nt < 2; ++nt) {
        int nl = nt * 16 + lr;
        bf16x8 bg[4];
        #pragma unroll
        for (int ks = 0; ks < 4; ++ks)
          bg[ks] = *reinterpret_cast<const bf16x8*>(
              Gl + nl * 256 + ((ks * 64 + lg * 16) ^ ((nl & 7) << 4)));
        f32x4 p = {0.f, 0.f, 0.f, 0.f};
        #pragma unroll
        for (int ks = 0; ks < 4; ++ks)
          p = __builtin_amdgcn_mfma_f32_16x16x32_bf16(af[ks], bg[ks], p, 0, 0, 0);
        // D[m][n]: 4 consecutive m, fixed n_local
        int mb0 = 2 * ((wv * 2 + j) * 16 + lg * 4);
        uint2 pk;
        pk.x = (unsigned)f2b(p[0]) | ((unsigned)f2b(p[1]) << 16);
        pk.y = (unsigned)f2b(p[2]) | ((unsigned)f2b(p[3]) << 16);
        *reinterpret_cast<uint2*>(Pl + nl * 256 + (mb0 ^ ((nl & 7) << 4))) = pk;
      }
    }
    __syncthreads();

    // ---- Phase C: oacc[n][p] += mfma(A=Pl rows n, B=SB rows p) ----
    // (no trailing barrier: next A writes Gl, untouched by C; bar1_{w+1} orders Pl)
    #pragma unroll
    for (int nt = 0; nt < 2; ++nt) {
      int nl = nt * 16 + lr;
      bf16x8 ap[4];
      #pragma unroll
      for (int ks = 0; ks < 4; ++ks)
        ap[ks] = *reinterpret_cast<const bf16x8*>(
            Pl + nl * 256 + ((ks * 64 + lg * 16) ^ ((nl & 7) << 4)));
      #pragma unroll
      for (int j = 0; j < 2; ++j) {
        int p = (wv * 2 + j) * 16 + lr;
        bf16x8 bs[4];
        #pragma unroll
        for (int ks = 0; ks < 4; ++ks)
          bs[ks] = *reinterpret_cast<const bf16x8*>(sb + p * 128 + ks * 32 + lg * 8);
        #pragma unroll
        for (int ks = 0; ks < 4; ++ks)
          oacc[nt][j] = __builtin_amdgcn_mfma_f32_16x16x32_bf16(ap[ks], bs[ks], oacc[nt][j], 0, 0, 0);
      }
    }
  }

  const float inv_scale = 0.08838834764831845f;
  float* ob = Out + (size_t)b * 16384;
  #pragma unroll
  for (int nt = 0; nt < 2; ++nt) {
    int gn = q * 32 + nt * 16 + lg * 4;
    #pragma unroll
    for (int j = 0; j < 2; ++j) {
      int p = (wv * 2 + j) * 16 + lr;
      #pragma unroll
      for (int r = 0; r < 4; ++r)
        ob[(gn + r) * 128 + p] = oacc[nt][j][r] * inv_scale;
    }
  }
}

extern "C" void kernel_launch(void* const* d_in, const int* in_sizes, int n_in,
                              void* d_out, int out_size, void* d_ws, size_t ws_size,
                              hipStream_t stream) {
  const float* flows = (const float*)d_in[0];
  const float* g1_wl = (const float*)d_in[10];
  const float* g1_bl = (const float*)d_in[11];
  const float* g1_wr = (const float*)d_in[12];
  const float* g2_wl = (const float*)d_in[13];
  const float* g2_bl = (const float*)d_in[14];
  const float* g2_wr = (const float*)d_in[15];
  const float* g3_wl = (const float*)d_in[16];
  const float* g3_bl = (const float*)d_in[17];
  const float* g3_wr = (const float*)d_in[18];
  const float* g4_wl = (const float*)d_in[19];
  const float* g4_bl = (const float*)d_in[20];
  const float* g4_wr = (const float*)d_in[21];
  const float* qsa   = (const float*)d_in[24];
  const float* ksa   = (const float*)d_in[25];
  const float* s2w   = (const float*)d_in[27];
  float* out = (float*)d_out;
  char* wsb  = (char*)d_ws;

  // workspace layout (bytes)
  ushort* FB16 = (ushort*)(wsb);                 // 32768*128 bf16 = 8388608
  ushort* SB   = (ushort*)(wsb + 8388608);       // 131072 bf16 = 262144
  ushort* WL   = (ushort*)(wsb + 8650752);       // 98304 bf16 = 196608
  ushort* WR   = (ushort*)(wsb + 8847360);       // 196608
  ushort* MBws = (ushort*)(wsb + 9043968);       // 131072 bf16 = 262144
  float*  C1   = (float*)(wsb + 9306112);        // 128*128 f32
  float*  C2   = (float*)(wsb + 9371648);        // 128*256 f32
  float*  C3   = (float*)(wsb + 9502720);
  float*  C4   = (float*)(wsb + 9568256);

  prep_all_k<<<896, 256, 0, stream>>>(s2w,
                                      g1_wl, g2_wl, g3_wl, g4_wl,
                                      g1_wr, g2_wr, g3_wr, g4_wr,
                                      SB, WL, WR);
  prep_mb_k<<<8, 256, 0, stream>>>(qsa, ksa, MBws);
  chain0_k<<<1, 256, 0, stream>>>(flows, WL, WR, g1_bl, g2_bl, g3_bl, C1, C2, C3, C4);
  sage_fused<<<512, 256, 0, stream>>>(flows, WR, g1_bl, g2_bl, g3_bl, g4_bl,
                                      C1, C2, C3, C4, FB16);
  attn_fused<<<1024, 256, 0, stream>>>(FB16, MBws, SB, out);
}

// Round 14
// 264.222 us; speedup vs baseline: 1.3030x; 1.0796x over previous
//
#include <hip/hip_runtime.h>
#include <math.h>

// Model_6150393168181 — fully bf16-MFMA pipeline.
// out[b] = (1/sqrt(128)) * sum_w (f qsa_w^T) (S_w f ksa_w^T)^T
// Re-associated:  R_w = f^T SB_w^T   Z = sum_w MB_w^T R_w   out = f @ Z / sqrt(128)
//   MB_w[e][d] = sum_{o'} ksa[w,o',e] qsa[w,o',d]  (prep, stored transposed: MBT[d][(w,e)])
// Z accumulates in VGPRs across workers (no P round-trip). attn grid = 256 b x 2 p-halves,
// 4 waves, 48 KB LDS (FT 32K + RT/ZT 16K shared), 3 blocks/CU.
// f = rms(relu(SAGE4(rms(flows)))); SAGE agg via corr_l = L @ (X_l @ wl_l^T) (chain0_k).

typedef __attribute__((ext_vector_type(8))) short bf16x8;
typedef __attribute__((ext_vector_type(4))) float f32x4;

__device__ inline ushort f2b(float x) {
  unsigned u = __builtin_bit_cast(unsigned, x);
  unsigned r = (u + 0x7fffu + ((u >> 16) & 1u)) >> 16;
  return (ushort)r;
}

// ---------------- prep: SB reorder + SAGE weight conversions ----------------
__global__ __launch_bounds__(256) void prep_all_k(
    const float* __restrict__ s2w,
    const float* __restrict__ wl1, const float* __restrict__ wl2,
    const float* __restrict__ wl3, const float* __restrict__ wl4,
    const float* __restrict__ wr1, const float* __restrict__ wr2,
    const float* __restrict__ wr3, const float* __restrict__ wr4,
    ushort* __restrict__ SB, ushort* __restrict__ WL, ushort* __restrict__ WR) {
  int i = blockIdx.x * 256 + threadIdx.x;
  if (i < 131072) {
    int w = i >> 14, p = (i >> 7) & 127, m = i & 127;
    SB[i] = f2b(s2w[p * 1024 + m * 8 + w]);
    return;
  }
  i -= 131072;
  if (i < 98304) {
    float v, u;
    if      (i < 16384) { v = wl1[i];         u = wr1[i]; }
    else if (i < 49152) { v = wl2[i - 16384]; u = wr2[i - 16384]; }
    else if (i < 81920) { v = wl3[i - 49152]; u = wr3[i - 49152]; }
    else                { v = wl4[i - 81920]; u = wr4[i - 81920]; }
    WL[i] = f2b(v);
    WR[i] = f2b(u);
  }
}

// ---------------- prep: MBT[d][(w,e)] = sum_{o'} ksa[w,o',e] * qsa[w,o',d] ----------------
__global__ __launch_bounds__(256, 1) void prep_mb_k(
    const float* __restrict__ qsa, const float* __restrict__ ksa,
    ushort* __restrict__ MBT) {
  __shared__ char QT[32768];   // QT[d][o'] = qsa[w][o'][d]
  __shared__ char KTm[32768];  // KTm[e][o'] = ksa[w][o'][e]
  int w = blockIdx.x, tid = threadIdx.x;
  const float* qw = qsa + (size_t)w * 16384;
  const float* kw = ksa + (size_t)w * 16384;
  for (int e = tid; e < 16384; e += 256) {
    int op = e >> 7, c = e & 127;
    int off = c * 256 + ((op * 2) ^ ((c & 7) << 4));
    *reinterpret_cast<ushort*>(QT + off)  = f2b(qw[e]);
    *reinterpret_cast<ushort*>(KTm + off) = f2b(kw[e]);
  }
  __syncthreads();
  int l = tid & 63, wv = tid >> 6, lr = l & 15, lg = l >> 4;
  #pragma unroll
  for (int rt = 0; rt < 2; ++rt) {
    int e = wv * 32 + rt * 16 + lr;
    bf16x8 a[4];
    #pragma unroll
    for (int ks = 0; ks < 4; ++ks)
      a[ks] = *reinterpret_cast<const bf16x8*>(KTm + e * 256 + ((ks * 64 + lg * 16) ^ ((e & 7) << 4)));
    #pragma unroll
    for (int ct = 0; ct < 8; ++ct) {
      int d = ct * 16 + lr;
      bf16x8 bq[4];
      #pragma unroll
      for (int ks = 0; ks < 4; ++ks)
        bq[ks] = *reinterpret_cast<const bf16x8*>(QT + d * 256 + ((ks * 64 + lg * 16) ^ ((d & 7) << 4)));
      f32x4 acc = {0.f, 0.f, 0.f, 0.f};
      #pragma unroll
      for (int ks = 0; ks < 4; ++ks)
        acc = __builtin_amdgcn_mfma_f32_16x16x32_bf16(a[ks], bq[ks], acc, 0, 0, 0);
      // D[e][d]: 4 consecutive e at fixed d -> MBT[d][w*128+e] packed uint2
      uint2 pk;
      pk.x = (unsigned)f2b(acc[0]) | ((unsigned)f2b(acc[1]) << 16);
      pk.y = (unsigned)f2b(acc[2]) | ((unsigned)f2b(acc[3]) << 16);
      *reinterpret_cast<uint2*>(&MBT[(size_t)(ct * 16 + lr) * 1024 + w * 128 + wv * 32 + rt * 16 + lg * 4]) = pk;
    }
  }
}

// ---------------- stage 128 rows (chain0 only): raw bf16 + rms scale ----------------
__device__ inline void stage_flows128(const float* __restrict__ flows, int blk,
                                      char* Xt, float* sArr, int wv, int lane) {
  for (int r = 0; r < 32; ++r) {
    int row = wv * 32 + r;
    const float2 v = *reinterpret_cast<const float2*>(
        flows + ((size_t)blk * 128 + row) * 128 + lane * 2);
    float ss = v.x * v.x + v.y * v.y;
    ss += __shfl_xor(ss, 32); ss += __shfl_xor(ss, 16); ss += __shfl_xor(ss, 8);
    ss += __shfl_xor(ss, 4);  ss += __shfl_xor(ss, 2);  ss += __shfl_xor(ss, 1);
    unsigned pk = (unsigned)f2b(v.x) | ((unsigned)f2b(v.y) << 16);
    *reinterpret_cast<unsigned*>(Xt + row * 256 + ((lane * 4) ^ ((row & 7) << 4))) = pk;
    if (lane == 0) sArr[row] = rsqrtf(ss * (1.0f / 128.0f));
  }
}

// ---------------- stage 64 rows (sage_fused): 8 unrolled float4 loads per wave ----------------
__device__ inline void stage_flows64(const float* __restrict__ flows, int blk,
                                     char* Xt, float* sArr, int wv, int lane) {
  int r2 = lane >> 5;
  int c4 = lane & 31;
  #pragma unroll
  for (int it = 0; it < 8; ++it) {
    int rowbase = wv * 16 + it * 2;
    const float4 v = *reinterpret_cast<const float4*>(
        flows + ((size_t)blk * 64 + rowbase) * 128 + lane * 4);
    int row = rowbase + r2;
    float ss = v.x * v.x + v.y * v.y + v.z * v.z + v.w * v.w;
    ss += __shfl_xor(ss, 16); ss += __shfl_xor(ss, 8);
    ss += __shfl_xor(ss, 4);  ss += __shfl_xor(ss, 2); ss += __shfl_xor(ss, 1);
    uint2 pk;
    pk.x = (unsigned)f2b(v.x) | ((unsigned)f2b(v.y) << 16);
    pk.y = (unsigned)f2b(v.z) | ((unsigned)f2b(v.w) << 16);
    *reinterpret_cast<uint2*>(Xt + row * 256 + ((c4 * 8) ^ ((row & 7) << 4))) = pk;
    if (c4 == 0) sArr[row] = rsqrtf(ss * (1.0f / 128.0f));
  }
}

// ---------------- mid SAGE layer (64-row block) ----------------
template <int K, int N>
__device__ inline void sage_layer_mid64(char* Xt, const float* sP, float* sN,
                                        const ushort* __restrict__ Wr,
                                        const float* __restrict__ bias,
                                        const float* __restrict__ corr, bool useCorr,
                                        int wv, int lr, int lg) {
  __syncthreads();
  bf16x8 a[K / 32];
  float sr[4];
  int rowA = wv * 16 + lr;
  #pragma unroll
  for (int ks = 0; ks < K / 32; ++ks)
    a[ks] = *reinterpret_cast<const bf16x8*>(
        Xt + rowA * (K * 2) + ((ks * 64 + lg * 16) ^ ((rowA & 7) << 4)));
  #pragma unroll
  for (int rr = 0; rr < 4; ++rr) sr[rr] = sP[wv * 16 + 4 * lg + rr];
  __syncthreads();
  float ssq[4] = {0.f, 0.f, 0.f, 0.f};
  #pragma unroll
  for (int nt = 0; nt < N / 16; ++nt) {
    int col = nt * 16 + lr;
    bf16x8 b[K / 32];
    #pragma unroll
    for (int ks = 0; ks < K / 32; ++ks)
      b[ks] = *reinterpret_cast<const bf16x8*>(Wr + col * K + ks * 32 + lg * 8);
    f32x4 acc = {0.f, 0.f, 0.f, 0.f};
    #pragma unroll
    for (int ks = 0; ks < K / 32; ++ks)
      acc = __builtin_amdgcn_mfma_f32_16x16x32_bf16(a[ks], b[ks], acc, 0, 0, 0);
    float bb = bias[col];
    #pragma unroll
    for (int rr = 0; rr < 4; ++rr) {
      int row = wv * 16 + 4 * lg + rr;
      float y = acc[rr] * sr[rr] + bb;
      if (useCorr) y += corr[row * N + col];
      *reinterpret_cast<ushort*>(Xt + row * (N * 2) + ((col * 2) ^ ((row & 7) << 4))) = f2b(y);
      ssq[rr] += y * y;
    }
  }
  #pragma unroll
  for (int rr = 0; rr < 4; ++rr) {
    float ss = ssq[rr];
    ss += __shfl_xor(ss, 1); ss += __shfl_xor(ss, 2);
    ss += __shfl_xor(ss, 4); ss += __shfl_xor(ss, 8);
    if (lr == 0) sN[wv * 16 + 4 * lg + rr] = 1.0f / fmaxf(sqrtf(ss), 1e-12f);
  }
}

// ---------------- last SAGE layer (64-row block) ----------------
__device__ inline void sage_layer_last64(char* Xt, const float* sP,
                                         const ushort* __restrict__ Wr,
                                         const float* __restrict__ bias,
                                         const float* __restrict__ corr, bool useCorr,
                                         int wv, int lr, int lg,
                                         ushort* __restrict__ Fg, int blk) {
  __syncthreads();
  bf16x8 a[4];
  float sr[4];
  int rowA = wv * 16 + lr;
  #pragma unroll
  for (int ks = 0; ks < 4; ++ks)
    a[ks] = *reinterpret_cast<const bf16x8*>(
        Xt + rowA * 256 + ((ks * 64 + lg * 16) ^ ((rowA & 7) << 4)));
  #pragma unroll
  for (int rr = 0; rr < 4; ++rr) sr[rr] = sP[wv * 16 + 4 * lg + rr];
  __syncthreads();
  float yreg[8][4];
  float ssq[4] = {0.f, 0.f, 0.f, 0.f};
  #pragma unroll
  for (int nt = 0; nt < 8; ++nt) {
    int col = nt * 16 + lr;
    bf16x8 b[4];
    #pragma unroll
    for (int ks = 0; ks < 4; ++ks)
      b[ks] = *reinterpret_cast<const bf16x8*>(Wr + col * 128 + ks * 32 + lg * 8);
    f32x4 acc = {0.f, 0.f, 0.f, 0.f};
    #pragma unroll
    for (int ks = 0; ks < 4; ++ks)
      acc = __builtin_amdgcn_mfma_f32_16x16x32_bf16(a[ks], b[ks], acc, 0, 0, 0);
    float bb = bias[col];
    #pragma unroll
    for (int rr = 0; rr < 4; ++rr) {
      int row = wv * 16 + 4 * lg + rr;
      float y = acc[rr] * sr[rr] + bb;
      if (useCorr) y += corr[row * 128 + col];
      yreg[nt][rr] = y;
      ssq[rr] += y * y;
    }
  }
  float inv[4], sc[4];
  #pragma unroll
  for (int rr = 0; rr < 4; ++rr) {
    float ss = ssq[rr];
    ss += __shfl_xor(ss, 1); ss += __shfl_xor(ss, 2);
    ss += __shfl_xor(ss, 4); ss += __shfl_xor(ss, 8);
    inv[rr] = 1.0f / fmaxf(sqrtf(ss), 1e-12f);
  }
  float ss2[4] = {0.f, 0.f, 0.f, 0.f};
  #pragma unroll
  for (int nt = 0; nt < 8; ++nt)
    #pragma unroll
    for (int rr = 0; rr < 4; ++rr) {
      float v = fmaxf(yreg[nt][rr] * inv[rr], 0.f);
      yreg[nt][rr] = v;
      ss2[rr] += v * v;
    }
  #pragma unroll
  for (int rr = 0; rr < 4; ++rr) {
    float ss = ss2[rr];
    ss += __shfl_xor(ss, 1); ss += __shfl_xor(ss, 2);
    ss += __shfl_xor(ss, 4); ss += __shfl_xor(ss, 8);
    sc[rr] = sqrtf(128.0f / fmaxf(ss, 1e-20f));
  }
  #pragma unroll
  for (int nt = 0; nt < 8; ++nt)
    #pragma unroll
    for (int rr = 0; rr < 4; ++rr) {
      int row = wv * 16 + 4 * lg + rr;
      Fg[((size_t)blk * 64 + row) * 128 + nt * 16 + lr] = f2b(yreg[nt][rr] * sc[rr]);
    }
}

// ---------------- K2: fused SAGE, 512 blocks x 64 rows ----------------
__global__ __launch_bounds__(256, 2) void sage_fused(
    const float* __restrict__ flows, const ushort* __restrict__ WR,
    const float* __restrict__ bl1, const float* __restrict__ bl2,
    const float* __restrict__ bl3, const float* __restrict__ bl4,
    const float* __restrict__ C1, const float* __restrict__ C2,
    const float* __restrict__ C3, const float* __restrict__ C4,
    ushort* __restrict__ Fg) {
  __shared__ char Xt[32768];
  __shared__ float sA[64], sB[64];
  int blk = blockIdx.x, tid = threadIdx.x;
  int lane = tid & 63, wv = tid >> 6, lr = lane & 15, lg = lane >> 4;
  stage_flows64(flows, blk, Xt, sA, wv, lane);
  bool c = (blk < 2);
  int ro = c ? blk * 64 : 0;
  sage_layer_mid64<128, 128>(Xt, sA, sB, WR + 0,     bl1, C1 + ro * 128, c, wv, lr, lg);
  sage_layer_mid64<128, 256>(Xt, sB, sA, WR + 16384, bl2, C2 + ro * 256, c, wv, lr, lg);
  sage_layer_mid64<256, 128>(Xt, sA, sB, WR + 49152, bl3, C3 + ro * 128, c, wv, lr, lg);
  sage_layer_last64(Xt, sB, WR + 81920, bl4, C4 + ro * 128, c, wv, lr, lg, Fg, blk);
}

// ---------------- K1: batch-0 chain -> corr tables (128 rows, 1 block) ----------------
template <int K, int N, bool CORRONLY>
__device__ inline void chain_layer(char* Xt, char* C0T, const float* sP, float* sN,
                                   const ushort* __restrict__ Wl, const ushort* __restrict__ Wr,
                                   const float* __restrict__ bias, float* __restrict__ Cg,
                                   int wv, int lr, int lg) {
  __syncthreads();
  bf16x8 a[2][K / 32];
  float sr[2][4];
  #pragma unroll
  for (int m = 0; m < 2; ++m) {
    int rowA = wv * 32 + m * 16 + lr;
    #pragma unroll
    for (int ks = 0; ks < K / 32; ++ks)
      a[m][ks] = *reinterpret_cast<const bf16x8*>(
          Xt + rowA * (K * 2) + ((ks * 64 + lg * 16) ^ ((rowA & 7) << 4)));
    #pragma unroll
    for (int rr = 0; rr < 4; ++rr) sr[m][rr] = sP[wv * 32 + m * 16 + 4 * lg + rr];
  }
  __syncthreads();
  #pragma unroll
  for (int nt = 0; nt < N / 16; ++nt) {
    int col = nt * 16 + lr;
    bf16x8 b[K / 32];
    #pragma unroll
    for (int ks = 0; ks < K / 32; ++ks)
      b[ks] = *reinterpret_cast<const bf16x8*>(Wl + col * K + ks * 32 + lg * 8);
    f32x4 acc[2] = {{0.f, 0.f, 0.f, 0.f}, {0.f, 0.f, 0.f, 0.f}};
    #pragma unroll
    for (int ks = 0; ks < K / 32; ++ks) {
      acc[0] = __builtin_amdgcn_mfma_f32_16x16x32_bf16(a[0][ks], b[ks], acc[0], 0, 0, 0);
      acc[1] = __builtin_amdgcn_mfma_f32_16x16x32_bf16(a[1][ks], b[ks], acc[1], 0, 0, 0);
    }
    #pragma unroll
    for (int m = 0; m < 2; ++m)
      #pragma unroll
      for (int rr = 0; rr < 4; ++rr) {
        int row = wv * 32 + m * 16 + 4 * lg + rr;
        *reinterpret_cast<ushort*>(C0T + col * 256 + ((row * 2) ^ ((col & 7) << 4))) =
            f2b(acc[m][rr] * sr[m][rr]);
      }
  }
  __syncthreads();
  bf16x8 aL[2][4];
  #pragma unroll
  for (int m = 0; m < 2; ++m) {
    int rowL = wv * 32 + m * 16 + lr;
    ushort iv = f2b(1.0f / (float)(rowL > 1 ? rowL : 1));
    #pragma unroll
    for (int ks = 0; ks < 4; ++ks)
      #pragma unroll
      for (int j = 0; j < 8; ++j) {
        int k = ks * 32 + lg * 8 + j;
        aL[m][ks][j] = (short)((k < rowL) ? iv : 0);
      }
  }
  float ssq[2][4] = {{0.f, 0.f, 0.f, 0.f}, {0.f, 0.f, 0.f, 0.f}};
  #pragma unroll
  for (int nt = 0; nt < N / 16; ++nt) {
    int col = nt * 16 + lr;
    bf16x8 bc[4];
    #pragma unroll
    for (int ks = 0; ks < 4; ++ks)
      bc[ks] = *reinterpret_cast<const bf16x8*>(
          C0T + col * 256 + ((ks * 64 + lg * 16) ^ ((col & 7) << 4)));
    f32x4 cacc[2] = {{0.f, 0.f, 0.f, 0.f}, {0.f, 0.f, 0.f, 0.f}};
    #pragma unroll
    for (int ks = 0; ks < 4; ++ks) {
      cacc[0] = __builtin_amdgcn_mfma_f32_16x16x32_bf16(aL[0][ks], bc[ks], cacc[0], 0, 0, 0);
      cacc[1] = __builtin_amdgcn_mfma_f32_16x16x32_bf16(aL[1][ks], bc[ks], cacc[1], 0, 0, 0);
    }
    #pragma unroll
    for (int m = 0; m < 2; ++m)
      #pragma unroll
      for (int rr = 0; rr < 4; ++rr) {
        int row = wv * 32 + m * 16 + 4 * lg + rr;
        Cg[row * N + col] = cacc[m][rr];
      }
    if (!CORRONLY) {
      bf16x8 b[K / 32];
      #pragma unroll
      for (int ks = 0; ks < K / 32; ++ks)
        b[ks] = *reinterpret_cast<const bf16x8*>(Wr + col * K + ks * 32 + lg * 8);
      f32x4 acc[2] = {{0.f, 0.f, 0.f, 0.f}, {0.f, 0.f, 0.f, 0.f}};
      #pragma unroll
      for (int ks = 0; ks < K / 32; ++ks) {
        acc[0] = __builtin_amdgcn_mfma_f32_16x16x32_bf16(a[0][ks], b[ks], acc[0], 0, 0, 0);
        acc[1] = __builtin_amdgcn_mfma_f32_16x16x32_bf16(a[1][ks], b[ks], acc[1], 0, 0, 0);
      }
      float bb = bias[col];
      #pragma unroll
      for (int m = 0; m < 2; ++m)
        #pragma unroll
        for (int rr = 0; rr < 4; ++rr) {
          int row = wv * 32 + m * 16 + 4 * lg + rr;
          float y = acc[m][rr] * sr[m][rr] + bb + cacc[m][rr];
          *reinterpret_cast<ushort*>(Xt + row * (N * 2) + ((col * 2) ^ ((row & 7) << 4))) = f2b(y);
          ssq[m][rr] += y * y;
        }
    }
  }
  if (!CORRONLY) {
    #pragma unroll
    for (int m = 0; m < 2; ++m)
      #pragma unroll
      for (int rr = 0; rr < 4; ++rr) {
        float ss = ssq[m][rr];
        ss += __shfl_xor(ss, 1); ss += __shfl_xor(ss, 2);
        ss += __shfl_xor(ss, 4); ss += __shfl_xor(ss, 8);
        if (lr == 0) sN[wv * 32 + m * 16 + 4 * lg + rr] = 1.0f / fmaxf(sqrtf(ss), 1e-12f);
      }
  }
}

__global__ __launch_bounds__(256, 1) void chain0_k(
    const float* __restrict__ flows, const ushort* __restrict__ WL, const ushort* __restrict__ WR,
    const float* __restrict__ bl1, const float* __restrict__ bl2, const float* __restrict__ bl3,
    float* __restrict__ C1, float* __restrict__ C2, float* __restrict__ C3, float* __restrict__ C4) {
  __shared__ char Xt[65536];
  __shared__ char C0T[65536];
  __shared__ float sA[128], sB[128];
  int tid = threadIdx.x;
  int lane = tid & 63, wv = tid >> 6, lr = lane & 15, lg = lane >> 4;
  stage_flows128(flows, 0, Xt, sA, wv, lane);
  chain_layer<128, 128, false>(Xt, C0T, sA, sB, WL + 0,     WR + 0,     bl1, C1, wv, lr, lg);
  chain_layer<128, 256, false>(Xt, C0T, sB, sA, WL + 16384, WR + 16384, bl2, C2, wv, lr, lg);
  chain_layer<256, 128, false>(Xt, C0T, sA, sB, WL + 49152, WR + 49152, bl3, C3, wv, lr, lg);
  chain_layer<128, 128, true >(Xt, C0T, sB, sA, WL + 81920, WR + 81920, nullptr, C4, wv, lr, lg);
}

// ---------------- fused attention v4 (Z-route): 512 blocks = 256 b x 2 p-halves ----------------
// Per worker w:  R: D[e][p] = mfma(A=FT rows e, B=SB_w rows p) -> RT[p][e] (packed uint2)
//                Z: zacc[d][p] += mfma(A=MBT rows d (k=(w,e)), B=RT rows p (k=e))
// Epilogue: ZT[p][d] <- zacc (packed); out[n][p] = mfma(A=f rows n (regs), B=ZT rows p)/sqrt(128)
__global__ __launch_bounds__(256, 3) void attn_fused(
    const ushort* __restrict__ F, const ushort* __restrict__ MBT,
    const ushort* __restrict__ SB, float* __restrict__ Out) {
  __shared__ char FT[32768];   // FT[e][m] = f[m][e], 128 rows x 256B, swizzled
  __shared__ char RT[16384];   // RT[p][e] 64 rows x 256B (reused as ZT[p][d])

  const int bq = blockIdx.x;
  const int b = bq >> 1, ph = bq & 1;
  const int tid = threadIdx.x;
  const int l = tid & 63, wv = tid >> 6;
  const int lr = l & 15, lg = l >> 4;

  const ushort* Fb = F + (size_t)b * 16384;

  // stage FT (transpose of f)
  #pragma unroll
  for (int it = 0; it < 8; ++it) {
    int idx = tid + it * 256;              // 0..2047
    int m = idx >> 4, eg = idx & 15;
    uint4 v = *reinterpret_cast<const uint4*>(Fb + m * 128 + eg * 8);
    const ushort* pv = reinterpret_cast<const ushort*>(&v);
    #pragma unroll
    for (int j = 0; j < 8; ++j) {
      int e = eg * 8 + j;
      *reinterpret_cast<ushort*>(FT + e * 256 + ((m * 2) ^ ((e & 7) << 4))) = pv[j];
    }
  }

  // hoist final-phase A-frags: f rows n (wave owns 2 n-tiles)
  bf16x8 fa[2][4];
  #pragma unroll
  for (int nt = 0; nt < 2; ++nt) {
    int n = wv * 32 + nt * 16 + lr;
    #pragma unroll
    for (int ks = 0; ks < 4; ++ks)
      fa[nt][ks] = *reinterpret_cast<const bf16x8*>(Fb + n * 128 + ks * 32 + lg * 8);
  }
  __syncthreads();

  f32x4 zacc[2][4];
  #pragma unroll
  for (int dt = 0; dt < 2; ++dt)
    #pragma unroll
    for (int pt = 0; pt < 4; ++pt) zacc[dt][pt] = f32x4{0.f, 0.f, 0.f, 0.f};

  for (int w = 0; w < 8; ++w) {
    const ushort* sb = SB + w * 16384 + ph * 64 * 128;   // rows p of this half

    // ---- Phase R: RT[p][e] ----
    #pragma unroll
    for (int et = 0; et < 2; ++et) {
      int e = wv * 32 + et * 16 + lr;
      bf16x8 af[4];
      #pragma unroll
      for (int ks = 0; ks < 4; ++ks)
        af[ks] = *reinterpret_cast<const bf16x8*>(
            FT + e * 256 + ((ks * 64 + lg * 16) ^ ((e & 7) << 4)));
      #pragma unroll
      for (int pt = 0; pt < 4; ++pt) {
        int p = pt * 16 + lr;   // local row in RT
        bf16x8 bs[4];
        #pragma unroll
        for (int ks = 0; ks < 4; ++ks)
          bs[ks] = *reinterpret_cast<const bf16x8*>(sb + p * 128 + ks * 32 + lg * 8);
        f32x4 rr = {0.f, 0.f, 0.f, 0.f};
        #pragma unroll
        for (int ks = 0; ks < 4; ++ks)
          rr = __builtin_amdgcn_mfma_f32_16x16x32_bf16(af[ks], bs[ks], rr, 0, 0, 0);
        // D[e][p]: 4 consecutive e at fixed p -> RT[p][e] packed
        int eb0 = 2 * (wv * 32 + et * 16 + lg * 4);
        uint2 pk;
        pk.x = (unsigned)f2b(rr[0]) | ((unsigned)f2b(rr[1]) << 16);
        pk.y = (unsigned)f2b(rr[2]) | ((unsigned)f2b(rr[3]) << 16);
        *reinterpret_cast<uint2*>(RT + p * 256 + (eb0 ^ ((p & 7) << 4))) = pk;
      }
    }
    __syncthreads();

    // ---- Phase Z: zacc += MBT_w (x) RT ----
    #pragma unroll
    for (int dt = 0; dt < 2; ++dt) {
      int d = wv * 32 + dt * 16 + lr;
      bf16x8 mf[4];
      #pragma unroll
      for (int ks = 0; ks < 4; ++ks)
        mf[ks] = *reinterpret_cast<const bf16x8*>(MBT + (size_t)d * 1024 + w * 128 + ks * 32 + lg * 8);
      #pragma unroll
      for (int pt = 0; pt < 4; ++pt) {
        int p = pt * 16 + lr;
        bf16x8 bg[4];
        #pragma unroll
        for (int ks = 0; ks < 4; ++ks)
          bg[ks] = *reinterpret_cast<const bf16x8*>(
              RT + p * 256 + ((ks * 64 + lg * 16) ^ ((p & 7) << 4)));
        #pragma unroll
        for (int ks = 0; ks < 4; ++ks)
          zacc[dt][pt] = __builtin_amdgcn_mfma_f32_16x16x32_bf16(mf[ks], bg[ks], zacc[dt][pt], 0, 0, 0);
      }
    }
    __syncthreads();
  }

  // ---- write ZT[p][d] (into RT buffer) ----
  #pragma unroll
  for (int dt = 0; dt < 2; ++dt) {
    int db0 = 2 * (wv * 32 + dt * 16 + lg * 4);
    #pragma unroll
    for (int pt = 0; pt < 4; ++pt) {
      int p = pt * 16 + lr;
      uint2 pk;
      pk.x = (unsigned)f2b(zacc[dt][pt][0]) | ((unsigned)f2b(zacc[dt][pt][1]) << 16);
      pk.y = (unsigned)f2b(zacc[dt][pt][2]) | ((unsigned)f2b(zacc[dt][pt][3]) << 16);
      *reinterpret_cast<uint2*>(RT + p * 256 + (db0 ^ ((p & 7) << 4))) = pk;
    }
  }
  __syncthreads();

  // ---- final: out[n][p] = (1/sqrt(128)) f @ Z ----
  const float inv_scale = 0.08838834764831845f;
  float* ob = Out + (size_t)b * 16384 + ph * 64;
  #pragma unroll
  for (int nt = 0; nt < 2; ++nt) {
    #pragma unroll
    for (int pt = 0; pt < 4; ++pt) {
      int p = pt * 16 + lr;
      bf16x8 bz[4];
      #pragma unroll
      for (int ks = 0; ks < 4; ++ks)
        bz[ks] = *reinterpret_cast<const bf16x8*>(
            RT + p * 256 + ((ks * 64 + lg * 16) ^ ((p & 7) << 4)));
      f32x4 oa = {0.f, 0.f, 0.f, 0.f};
      #pragma unroll
      for (int ks = 0; ks < 4; ++ks)
        oa = __builtin_amdgcn_mfma_f32_16x16x32_bf16(fa[nt][ks], bz[ks], oa, 0, 0, 0);
      int n0 = wv * 32 + nt * 16 + lg * 4;
      #pragma unroll
      for (int r = 0; r < 4; ++r)
        ob[(size_t)(n0 + r) * 128 + p] = oa[r] * inv_scale;
    }
  }
}

extern "C" void kernel_launch(void* const* d_in, const int* in_sizes, int n_in,
                              void* d_out, int out_size, void* d_ws, size_t ws_size,
                              hipStream_t stream) {
  const float* flows = (const float*)d_in[0];
  const float* g1_wl = (const float*)d_in[10];
  const float* g1_bl = (const float*)d_in[11];
  const float* g1_wr = (const float*)d_in[12];
  const float* g2_wl = (const float*)d_in[13];
  const float* g2_bl = (const float*)d_in[14];
  const float* g2_wr = (const float*)d_in[15];
  const float* g3_wl = (const float*)d_in[16];
  const float* g3_bl = (const float*)d_in[17];
  const float* g3_wr = (const float*)d_in[18];
  const float* g4_wl = (const float*)d_in[19];
  const float* g4_bl = (const float*)d_in[20];
  const float* g4_wr = (const float*)d_in[21];
  const float* qsa   = (const float*)d_in[24];
  const float* ksa   = (const float*)d_in[25];
  const float* s2w   = (const float*)d_in[27];
  float* out = (float*)d_out;
  char* wsb  = (char*)d_ws;

  // workspace layout (bytes)
  ushort* FB16 = (ushort*)(wsb);                 // 32768*128 bf16 = 8388608
  ushort* SB   = (ushort*)(wsb + 8388608);       // 131072 bf16 = 262144
  ushort* WL   = (ushort*)(wsb + 8650752);       // 98304 bf16 = 196608
  ushort* WR   = (ushort*)(wsb + 8847360);       // 196608
  ushort* MBT  = (ushort*)(wsb + 9043968);       // 128*1024 bf16 = 262144
  float*  C1   = (float*)(wsb + 9306112);        // 128*128 f32
  float*  C2   = (float*)(wsb + 9371648);        // 128*256 f32
  float*  C3   = (float*)(wsb + 9502720);
  float*  C4   = (float*)(wsb + 9568256);

  prep_all_k<<<896, 256, 0, stream>>>(s2w,
                                      g1_wl, g2_wl, g3_wl, g4_wl,
                                      g1_wr, g2_wr, g3_wr, g4_wr,
                                      SB, WL, WR);
  prep_mb_k<<<8, 256, 0, stream>>>(qsa, ksa, MBT);
  chain0_k<<<1, 256, 0, stream>>>(flows, WL, WR, g1_bl, g2_bl, g3_bl, C1, C2, C3, C4);
  sage_fused<<<512, 256, 0, stream>>>(flows, WR, g1_bl, g2_bl, g3_bl, g4_bl,
                                      C1, C2, C3, C4, FB16);
  attn_fused<<<512, 256, 0, stream>>>(FB16, MBT, SB, out);
}

// Round 15
// 257.159 us; speedup vs baseline: 1.3388x; 1.0275x over previous
//
#include <hip/hip_runtime.h>
#include <math.h>

// Model_6150393168181 — fully bf16-MFMA pipeline.
// out[b] = (1/sqrt(128)) * sum_w (f qsa_w^T) (S_w f ksa_w^T)^T
// Re-associated:  R_w = f^T SB_w^T   Z = sum_w MB_w^T R_w   out = f @ Z / sqrt(128)
//   MB_w[e][d] = sum_{o'} ksa[w,o',e] qsa[w,o',d]  (prep, stored transposed MBT[d][(w,e)])
// f = rms(relu(SAGE4(rms(flows)))); SAGE agg = exclusive-prefix-mean over batch-0 rows:
//   corr_l = L @ (s.X_l @ wl_l^T), applied only to rows 0..127.
// chain0_k (1024 thr, 16 waves, rows x8 / cols x2 split) computes the batch-0 chain
// incl. corr IN-REGISTER and writes F[0:128] directly; sage_fused (510 blocks) does
// rows 128..32767 with no corr. attn_fused = Z-route, 512 blocks, 3/CU.

typedef __attribute__((ext_vector_type(8))) short bf16x8;
typedef __attribute__((ext_vector_type(4))) float f32x4;

__device__ inline ushort f2b(float x) {
  unsigned u = __builtin_bit_cast(unsigned, x);
  unsigned r = (u + 0x7fffu + ((u >> 16) & 1u)) >> 16;
  return (ushort)r;
}

// ---------------- prep: SB reorder + SAGE weight conversions ----------------
__global__ __launch_bounds__(256) void prep_all_k(
    const float* __restrict__ s2w,
    const float* __restrict__ wl1, const float* __restrict__ wl2,
    const float* __restrict__ wl3, const float* __restrict__ wl4,
    const float* __restrict__ wr1, const float* __restrict__ wr2,
    const float* __restrict__ wr3, const float* __restrict__ wr4,
    ushort* __restrict__ SB, ushort* __restrict__ WL, ushort* __restrict__ WR) {
  int i = blockIdx.x * 256 + threadIdx.x;
  if (i < 131072) {
    int w = i >> 14, p = (i >> 7) & 127, m = i & 127;
    SB[i] = f2b(s2w[p * 1024 + m * 8 + w]);
    return;
  }
  i -= 131072;
  if (i < 98304) {
    float v, u;
    if      (i < 16384) { v = wl1[i];         u = wr1[i]; }
    else if (i < 49152) { v = wl2[i - 16384]; u = wr2[i - 16384]; }
    else if (i < 81920) { v = wl3[i - 49152]; u = wr3[i - 49152]; }
    else                { v = wl4[i - 81920]; u = wr4[i - 81920]; }
    WL[i] = f2b(v);
    WR[i] = f2b(u);
  }
}

// ---------------- prep: MBT[d][(w,e)] = sum_{o'} ksa[w,o',e] * qsa[w,o',d] ----------------
__global__ __launch_bounds__(256, 1) void prep_mb_k(
    const float* __restrict__ qsa, const float* __restrict__ ksa,
    ushort* __restrict__ MBT) {
  __shared__ char QT[32768];   // QT[d][o'] = qsa[w][o'][d]
  __shared__ char KTm[32768];  // KTm[e][o'] = ksa[w][o'][e]
  int w = blockIdx.x, tid = threadIdx.x;
  const float* qw = qsa + (size_t)w * 16384;
  const float* kw = ksa + (size_t)w * 16384;
  for (int e = tid; e < 16384; e += 256) {
    int op = e >> 7, c = e & 127;
    int off = c * 256 + ((op * 2) ^ ((c & 7) << 4));
    *reinterpret_cast<ushort*>(QT + off)  = f2b(qw[e]);
    *reinterpret_cast<ushort*>(KTm + off) = f2b(kw[e]);
  }
  __syncthreads();
  int l = tid & 63, wv = tid >> 6, lr = l & 15, lg = l >> 4;
  #pragma unroll
  for (int rt = 0; rt < 2; ++rt) {
    int e = wv * 32 + rt * 16 + lr;
    bf16x8 a[4];
    #pragma unroll
    for (int ks = 0; ks < 4; ++ks)
      a[ks] = *reinterpret_cast<const bf16x8*>(KTm + e * 256 + ((ks * 64 + lg * 16) ^ ((e & 7) << 4)));
    #pragma unroll
    for (int ct = 0; ct < 8; ++ct) {
      int d = ct * 16 + lr;
      bf16x8 bq[4];
      #pragma unroll
      for (int ks = 0; ks < 4; ++ks)
        bq[ks] = *reinterpret_cast<const bf16x8*>(QT + d * 256 + ((ks * 64 + lg * 16) ^ ((d & 7) << 4)));
      f32x4 acc = {0.f, 0.f, 0.f, 0.f};
      #pragma unroll
      for (int ks = 0; ks < 4; ++ks)
        acc = __builtin_amdgcn_mfma_f32_16x16x32_bf16(a[ks], bq[ks], acc, 0, 0, 0);
      uint2 pk;
      pk.x = (unsigned)f2b(acc[0]) | ((unsigned)f2b(acc[1]) << 16);
      pk.y = (unsigned)f2b(acc[2]) | ((unsigned)f2b(acc[3]) << 16);
      *reinterpret_cast<uint2*>(&MBT[(size_t)(ct * 16 + lr) * 1024 + w * 128 + wv * 32 + rt * 16 + lg * 4]) = pk;
    }
  }
}

// ---------------- stage 64 rows (sage_fused): 8 unrolled float4 loads per wave ----------------
__device__ inline void stage_flows64(const float* __restrict__ flows, int blk,
                                     char* Xt, float* sArr, int wv, int lane) {
  int r2 = lane >> 5;
  int c4 = lane & 31;
  #pragma unroll
  for (int it = 0; it < 8; ++it) {
    int rowbase = wv * 16 + it * 2;
    const float4 v = *reinterpret_cast<const float4*>(
        flows + ((size_t)blk * 64 + rowbase) * 128 + lane * 4);
    int row = rowbase + r2;
    float ss = v.x * v.x + v.y * v.y + v.z * v.z + v.w * v.w;
    ss += __shfl_xor(ss, 16); ss += __shfl_xor(ss, 8);
    ss += __shfl_xor(ss, 4);  ss += __shfl_xor(ss, 2); ss += __shfl_xor(ss, 1);
    uint2 pk;
    pk.x = (unsigned)f2b(v.x) | ((unsigned)f2b(v.y) << 16);
    pk.y = (unsigned)f2b(v.z) | ((unsigned)f2b(v.w) << 16);
    *reinterpret_cast<uint2*>(Xt + row * 256 + ((c4 * 8) ^ ((row & 7) << 4))) = pk;
    if (c4 == 0) sArr[row] = rsqrtf(ss * (1.0f / 128.0f));
  }
}

// ---------------- mid SAGE layer (64-row block, no corr) ----------------
template <int K, int N>
__device__ inline void sage_layer_mid64(char* Xt, const float* sP, float* sN,
                                        const ushort* __restrict__ Wr,
                                        const float* __restrict__ bias,
                                        int wv, int lr, int lg) {
  __syncthreads();
  bf16x8 a[K / 32];
  float sr[4];
  int rowA = wv * 16 + lr;
  #pragma unroll
  for (int ks = 0; ks < K / 32; ++ks)
    a[ks] = *reinterpret_cast<const bf16x8*>(
        Xt + rowA * (K * 2) + ((ks * 64 + lg * 16) ^ ((rowA & 7) << 4)));
  #pragma unroll
  for (int rr = 0; rr < 4; ++rr) sr[rr] = sP[wv * 16 + 4 * lg + rr];
  __syncthreads();
  float ssq[4] = {0.f, 0.f, 0.f, 0.f};
  #pragma unroll
  for (int nt = 0; nt < N / 16; ++nt) {
    int col = nt * 16 + lr;
    bf16x8 b[K / 32];
    #pragma unroll
    for (int ks = 0; ks < K / 32; ++ks)
      b[ks] = *reinterpret_cast<const bf16x8*>(Wr + col * K + ks * 32 + lg * 8);
    f32x4 acc = {0.f, 0.f, 0.f, 0.f};
    #pragma unroll
    for (int ks = 0; ks < K / 32; ++ks)
      acc = __builtin_amdgcn_mfma_f32_16x16x32_bf16(a[ks], b[ks], acc, 0, 0, 0);
    float bb = bias[col];
    #pragma unroll
    for (int rr = 0; rr < 4; ++rr) {
      int row = wv * 16 + 4 * lg + rr;
      float y = acc[rr] * sr[rr] + bb;
      *reinterpret_cast<ushort*>(Xt + row * (N * 2) + ((col * 2) ^ ((row & 7) << 4))) = f2b(y);
      ssq[rr] += y * y;
    }
  }
  #pragma unroll
  for (int rr = 0; rr < 4; ++rr) {
    float ss = ssq[rr];
    ss += __shfl_xor(ss, 1); ss += __shfl_xor(ss, 2);
    ss += __shfl_xor(ss, 4); ss += __shfl_xor(ss, 8);
    if (lr == 0) sN[wv * 16 + 4 * lg + rr] = 1.0f / fmaxf(sqrtf(ss), 1e-12f);
  }
}

// ---------------- last SAGE layer (64-row block, no corr) ----------------
__device__ inline void sage_layer_last64(char* Xt, const float* sP,
                                         const ushort* __restrict__ Wr,
                                         const float* __restrict__ bias,
                                         int wv, int lr, int lg,
                                         ushort* __restrict__ Fg, int blk) {
  __syncthreads();
  bf16x8 a[4];
  float sr[4];
  int rowA = wv * 16 + lr;
  #pragma unroll
  for (int ks = 0; ks < 4; ++ks)
    a[ks] = *reinterpret_cast<const bf16x8*>(
        Xt + rowA * 256 + ((ks * 64 + lg * 16) ^ ((rowA & 7) << 4)));
  #pragma unroll
  for (int rr = 0; rr < 4; ++rr) sr[rr] = sP[wv * 16 + 4 * lg + rr];
  __syncthreads();
  float yreg[8][4];
  float ssq[4] = {0.f, 0.f, 0.f, 0.f};
  #pragma unroll
  for (int nt = 0; nt < 8; ++nt) {
    int col = nt * 16 + lr;
    bf16x8 b[4];
    #pragma unroll
    for (int ks = 0; ks < 4; ++ks)
      b[ks] = *reinterpret_cast<const bf16x8*>(Wr + col * 128 + ks * 32 + lg * 8);
    f32x4 acc = {0.f, 0.f, 0.f, 0.f};
    #pragma unroll
    for (int ks = 0; ks < 4; ++ks)
      acc = __builtin_amdgcn_mfma_f32_16x16x32_bf16(a[ks], b[ks], acc, 0, 0, 0);
    float bb = bias[col];
    #pragma unroll
    for (int rr = 0; rr < 4; ++rr) {
      float y = acc[rr] * sr[rr] + bb;
      yreg[nt][rr] = y;
      ssq[rr] += y * y;
    }
  }
  float inv[4], sc[4];
  #pragma unroll
  for (int rr = 0; rr < 4; ++rr) {
    float ss = ssq[rr];
    ss += __shfl_xor(ss, 1); ss += __shfl_xor(ss, 2);
    ss += __shfl_xor(ss, 4); ss += __shfl_xor(ss, 8);
    inv[rr] = 1.0f / fmaxf(sqrtf(ss), 1e-12f);
  }
  float ss2[4] = {0.f, 0.f, 0.f, 0.f};
  #pragma unroll
  for (int nt = 0; nt < 8; ++nt)
    #pragma unroll
    for (int rr = 0; rr < 4; ++rr) {
      float v = fmaxf(yreg[nt][rr] * inv[rr], 0.f);
      yreg[nt][rr] = v;
      ss2[rr] += v * v;
    }
  #pragma unroll
  for (int rr = 0; rr < 4; ++rr) {
    float ss = ss2[rr];
    ss += __shfl_xor(ss, 1); ss += __shfl_xor(ss, 2);
    ss += __shfl_xor(ss, 4); ss += __shfl_xor(ss, 8);
    sc[rr] = sqrtf(128.0f / fmaxf(ss, 1e-20f));
  }
  #pragma unroll
  for (int nt = 0; nt < 8; ++nt)
    #pragma unroll
    for (int rr = 0; rr < 4; ++rr) {
      int row = wv * 16 + 4 * lg + rr;
      Fg[((size_t)blk * 64 + row) * 128 + nt * 16 + lr] = f2b(yreg[nt][rr] * sc[rr]);
    }
}

// ---------------- K2: fused SAGE, 510 blocks (rows 128..32767), no corr ----------------
__global__ __launch_bounds__(256, 2) void sage_fused(
    const float* __restrict__ flows, const ushort* __restrict__ WR,
    const float* __restrict__ bl1, const float* __restrict__ bl2,
    const float* __restrict__ bl3, const float* __restrict__ bl4,
    ushort* __restrict__ Fg) {
  __shared__ char Xt[32768];
  __shared__ float sA[64], sB[64];
  int blk = blockIdx.x + 2, tid = threadIdx.x;
  int lane = tid & 63, wv = tid >> 6, lr = lane & 15, lg = lane >> 4;
  stage_flows64(flows, blk, Xt, sA, wv, lane);
  sage_layer_mid64<128, 128>(Xt, sA, sB, WR + 0,     bl1, wv, lr, lg);
  sage_layer_mid64<128, 256>(Xt, sB, sA, WR + 16384, bl2, wv, lr, lg);
  sage_layer_mid64<256, 128>(Xt, sA, sB, WR + 49152, bl3, wv, lr, lg);
  sage_layer_last64(Xt, sB, WR + 81920, bl4, wv, lr, lg, Fg, blk);
}

// ---------------- K1: batch-0 chain, 16 waves (rows x8, cols x2), writes F[0:128] ----------------
template <int K, int N, bool LAST>
__device__ inline void chain_layer16(char* Xt, char* C0T, const float* sP, float* sN,
                                     float* red,
                                     const ushort* __restrict__ Wl, const ushort* __restrict__ Wr,
                                     const float* __restrict__ bias,
                                     ushort* __restrict__ Fg,
                                     int wr, int wc, int lr, int lg) {
  __syncthreads();
  bf16x8 a[K / 32];
  float sr[4];
  int rowA = wr * 16 + lr;
  #pragma unroll
  for (int ks = 0; ks < K / 32; ++ks)
    a[ks] = *reinterpret_cast<const bf16x8*>(
        Xt + rowA * (K * 2) + ((ks * 64 + lg * 16) ^ ((rowA & 7) << 4)));
  #pragma unroll
  for (int rr = 0; rr < 4; ++rr) sr[rr] = sP[wr * 16 + 4 * lg + rr];

  // pass1: C0 = s.X @ Wl^T -> C0T[col][i] (packed uint2 along rows)
  #pragma unroll
  for (int nt = 0; nt < N / 32; ++nt) {
    int col = wc * (N / 2) + nt * 16 + lr;
    bf16x8 b[K / 32];
    #pragma unroll
    for (int ks = 0; ks < K / 32; ++ks)
      b[ks] = *reinterpret_cast<const bf16x8*>(Wl + col * K + ks * 32 + lg * 8);
    f32x4 acc = {0.f, 0.f, 0.f, 0.f};
    #pragma unroll
    for (int ks = 0; ks < K / 32; ++ks)
      acc = __builtin_amdgcn_mfma_f32_16x16x32_bf16(a[ks], b[ks], acc, 0, 0, 0);
    uint2 pk;
    pk.x = (unsigned)f2b(acc[0] * sr[0]) | ((unsigned)f2b(acc[1] * sr[1]) << 16);
    pk.y = (unsigned)f2b(acc[2] * sr[2]) | ((unsigned)f2b(acc[3] * sr[3]) << 16);
    *reinterpret_cast<uint2*>(C0T + col * 256 + ((2 * (wr * 16 + lg * 4)) ^ ((col & 7) << 4))) = pk;
  }
  __syncthreads();

  // triangular L fragments for this wave's rows
  bf16x8 aL[4];
  int rowL = wr * 16 + lr;
  ushort iv = f2b(1.0f / (float)(rowL > 1 ? rowL : 1));
  #pragma unroll
  for (int ks = 0; ks < 4; ++ks)
    #pragma unroll
    for (int j = 0; j < 8; ++j) {
      int k = ks * 32 + lg * 8 + j;
      aL[ks][j] = (short)((k < rowL) ? iv : 0);
    }

  // pass2: y = s.X@Wr^T + b + (L@C0)
  float ssq[4] = {0.f, 0.f, 0.f, 0.f};
  float yreg[4][4];
  #pragma unroll
  for (int nt = 0; nt < N / 32; ++nt) {
    int col = wc * (N / 2) + nt * 16 + lr;
    bf16x8 bc[4];
    #pragma unroll
    for (int ks = 0; ks < 4; ++ks)
      bc[ks] = *reinterpret_cast<const bf16x8*>(
          C0T + col * 256 + ((ks * 64 + lg * 16) ^ ((col & 7) << 4)));
    f32x4 cacc = {0.f, 0.f, 0.f, 0.f};
    #pragma unroll
    for (int ks = 0; ks < 4; ++ks)
      cacc = __builtin_amdgcn_mfma_f32_16x16x32_bf16(aL[ks], bc[ks], cacc, 0, 0, 0);
    bf16x8 b[K / 32];
    #pragma unroll
    for (int ks = 0; ks < K / 32; ++ks)
      b[ks] = *reinterpret_cast<const bf16x8*>(Wr + col * K + ks * 32 + lg * 8);
    f32x4 acc = {0.f, 0.f, 0.f, 0.f};
    #pragma unroll
    for (int ks = 0; ks < K / 32; ++ks)
      acc = __builtin_amdgcn_mfma_f32_16x16x32_bf16(a[ks], b[ks], acc, 0, 0, 0);
    float bb = bias[col];
    #pragma unroll
    for (int rr = 0; rr < 4; ++rr) {
      float y = acc[rr] * sr[rr] + bb + cacc[rr];
      if (!LAST) {
        int row = wr * 16 + lg * 4 + rr;
        *reinterpret_cast<ushort*>(Xt + row * (N * 2) + ((col * 2) ^ ((row & 7) << 4))) = f2b(y);
      } else {
        yreg[nt][rr] = y;
      }
      ssq[rr] += y * y;
    }
  }
  // row-norm: partial over this wave's cols -> red[wc][row], combine
  #pragma unroll
  for (int rr = 0; rr < 4; ++rr) {
    float ss = ssq[rr];
    ss += __shfl_xor(ss, 1); ss += __shfl_xor(ss, 2);
    ss += __shfl_xor(ss, 4); ss += __shfl_xor(ss, 8);
    if (lr == 0) red[wc * 128 + wr * 16 + 4 * lg + rr] = ss;
  }
  __syncthreads();
  if (!LAST) {
    if (wc == 0 && lr == 0) {
      #pragma unroll
      for (int rr = 0; rr < 4; ++rr) {
        int row = wr * 16 + 4 * lg + rr;
        float t = red[row] + red[128 + row];
        sN[row] = 1.0f / fmaxf(sqrtf(t), 1e-12f);
      }
    }
  } else {
    float inv[4];
    #pragma unroll
    for (int rr = 0; rr < 4; ++rr) {
      int row = wr * 16 + 4 * lg + rr;
      inv[rr] = 1.0f / fmaxf(sqrtf(red[row] + red[128 + row]), 1e-12f);
    }
    float ss2[4] = {0.f, 0.f, 0.f, 0.f};
    #pragma unroll
    for (int nt = 0; nt < 4; ++nt)
      #pragma unroll
      for (int rr = 0; rr < 4; ++rr) {
        float v = fmaxf(yreg[nt][rr] * inv[rr], 0.f);
        yreg[nt][rr] = v;
        ss2[rr] += v * v;
      }
    __syncthreads();  // all red reads done
    #pragma unroll
    for (int rr = 0; rr < 4; ++rr) {
      float ss = ss2[rr];
      ss += __shfl_xor(ss, 1); ss += __shfl_xor(ss, 2);
      ss += __shfl_xor(ss, 4); ss += __shfl_xor(ss, 8);
      if (lr == 0) red[wc * 128 + wr * 16 + 4 * lg + rr] = ss;
    }
    __syncthreads();
    #pragma unroll
    for (int rr = 0; rr < 4; ++rr) {
      int row = wr * 16 + 4 * lg + rr;
      float sc = sqrtf(128.0f / fmaxf(red[row] + red[128 + row], 1e-20f));
      #pragma unroll
      for (int nt = 0; nt < 4; ++nt)
        Fg[(size_t)row * 128 + wc * 64 + nt * 16 + lr] = f2b(yreg[nt][rr] * sc);
    }
  }
}

__global__ __launch_bounds__(1024, 1) void chain0_k(
    const float* __restrict__ flows, const ushort* __restrict__ WL, const ushort* __restrict__ WR,
    const float* __restrict__ bl1, const float* __restrict__ bl2,
    const float* __restrict__ bl3, const float* __restrict__ bl4,
    ushort* __restrict__ Fg) {
  __shared__ char Xt[65536];
  __shared__ char C0T[65536];
  __shared__ float sA[128], sB[128];
  __shared__ float red[256];
  int tid = threadIdx.x;
  int lane = tid & 63, wv = tid >> 6;
  int wr = wv >> 1, wc = wv & 1;
  int lr = lane & 15, lg = lane >> 4;

  // stage batch-0 flows (128x128 f32) as swizzled bf16 + rms scales
  #pragma unroll
  for (int it = 0; it < 4; ++it) {
    int idx = tid + it * 1024;
    int row = idx >> 5, c4 = idx & 31;
    const float4 v = *reinterpret_cast<const float4*>(flows + (size_t)row * 128 + c4 * 4);
    float ss = v.x * v.x + v.y * v.y + v.z * v.z + v.w * v.w;
    ss += __shfl_xor(ss, 16); ss += __shfl_xor(ss, 8);
    ss += __shfl_xor(ss, 4);  ss += __shfl_xor(ss, 2); ss += __shfl_xor(ss, 1);
    uint2 pk;
    pk.x = (unsigned)f2b(v.x) | ((unsigned)f2b(v.y) << 16);
    pk.y = (unsigned)f2b(v.z) | ((unsigned)f2b(v.w) << 16);
    *reinterpret_cast<uint2*>(Xt + row * 256 + ((c4 * 8) ^ ((row & 7) << 4))) = pk;
    if ((tid & 31) == 0) sA[row] = rsqrtf(ss * (1.0f / 128.0f));
  }

  chain_layer16<128, 128, false>(Xt, C0T, sA, sB, red, WL + 0,     WR + 0,     bl1, nullptr, wr, wc, lr, lg);
  chain_layer16<128, 256, false>(Xt, C0T, sB, sA, red, WL + 16384, WR + 16384, bl2, nullptr, wr, wc, lr, lg);
  chain_layer16<256, 128, false>(Xt, C0T, sA, sB, red, WL + 49152, WR + 49152, bl3, nullptr, wr, wc, lr, lg);
  chain_layer16<128, 128, true >(Xt, C0T, sB, sA, red, WL + 81920, WR + 81920, bl4, Fg,      wr, wc, lr, lg);
}

// ---------------- fused attention v4 (Z-route): 512 blocks = 256 b x 2 p-halves ----------------
__global__ __launch_bounds__(256, 3) void attn_fused(
    const ushort* __restrict__ F, const ushort* __restrict__ MBT,
    const ushort* __restrict__ SB, float* __restrict__ Out) {
  __shared__ char FT[32768];   // FT[e][m] = f[m][e], swizzled
  __shared__ char RT[16384];   // RT[p][e] (reused as ZT[p][d])

  const int bq = blockIdx.x;
  const int b = bq >> 1, ph = bq & 1;
  const int tid = threadIdx.x;
  const int l = tid & 63, wv = tid >> 6;
  const int lr = l & 15, lg = l >> 4;

  const ushort* Fb = F + (size_t)b * 16384;

  #pragma unroll
  for (int it = 0; it < 8; ++it) {
    int idx = tid + it * 256;
    int m = idx >> 4, eg = idx & 15;
    uint4 v = *reinterpret_cast<const uint4*>(Fb + m * 128 + eg * 8);
    const ushort* pv = reinterpret_cast<const ushort*>(&v);
    #pragma unroll
    for (int j = 0; j < 8; ++j) {
      int e = eg * 8 + j;
      *reinterpret_cast<ushort*>(FT + e * 256 + ((m * 2) ^ ((e & 7) << 4))) = pv[j];
    }
  }

  bf16x8 fa[2][4];
  #pragma unroll
  for (int nt = 0; nt < 2; ++nt) {
    int n = wv * 32 + nt * 16 + lr;
    #pragma unroll
    for (int ks = 0; ks < 4; ++ks)
      fa[nt][ks] = *reinterpret_cast<const bf16x8*>(Fb + n * 128 + ks * 32 + lg * 8);
  }
  __syncthreads();

  f32x4 zacc[2][4];
  #pragma unroll
  for (int dt = 0; dt < 2; ++dt)
    #pragma unroll
    for (int pt = 0; pt < 4; ++pt) zacc[dt][pt] = f32x4{0.f, 0.f, 0.f, 0.f};

  for (int w = 0; w < 8; ++w) {
    const ushort* sb = SB + w * 16384 + ph * 64 * 128;

    #pragma unroll
    for (int et = 0; et < 2; ++et) {
      int e = wv * 32 + et * 16 + lr;
      bf16x8 af[4];
      #pragma unroll
      for (int ks = 0; ks < 4; ++ks)
        af[ks] = *reinterpret_cast<const bf16x8*>(
            FT + e * 256 + ((ks * 64 + lg * 16) ^ ((e & 7) << 4)));
      #pragma unroll
      for (int pt = 0; pt < 4; ++pt) {
        int p = pt * 16 + lr;
        bf16x8 bs[4];
        #pragma unroll
        for (int ks = 0; ks < 4; ++ks)
          bs[ks] = *reinterpret_cast<const bf16x8*>(sb + p * 128 + ks * 32 + lg * 8);
        f32x4 rr = {0.f, 0.f, 0.f, 0.f};
        #pragma unroll
        for (int ks = 0; ks < 4; ++ks)
          rr = __builtin_amdgcn_mfma_f32_16x16x32_bf16(af[ks], bs[ks], rr, 0, 0, 0);
        int eb0 = 2 * (wv * 32 + et * 16 + lg * 4);
        uint2 pk;
        pk.x = (unsigned)f2b(rr[0]) | ((unsigned)f2b(rr[1]) << 16);
        pk.y = (unsigned)f2b(rr[2]) | ((unsigned)f2b(rr[3]) << 16);
        *reinterpret_cast<uint2*>(RT + p * 256 + (eb0 ^ ((p & 7) << 4))) = pk;
      }
    }
    __syncthreads();

    #pragma unroll
    for (int dt = 0; dt < 2; ++dt) {
      int d = wv * 32 + dt * 16 + lr;
      bf16x8 mf[4];
      #pragma unroll
      for (int ks = 0; ks < 4; ++ks)
        mf[ks] = *reinterpret_cast<const bf16x8*>(MBT + (size_t)d * 1024 + w * 128 + ks * 32 + lg * 8);
      #pragma unroll
      for (int pt = 0; pt < 4; ++pt) {
        int p = pt * 16 + lr;
        bf16x8 bg[4];
        #pragma unroll
        for (int ks = 0; ks < 4; ++ks)
          bg[ks] = *reinterpret_cast<const bf16x8*>(
              RT + p * 256 + ((ks * 64 + lg * 16) ^ ((p & 7) << 4)));
        #pragma unroll
        for (int ks = 0; ks < 4; ++ks)
          zacc[dt][pt] = __builtin_amdgcn_mfma_f32_16x16x32_bf16(mf[ks], bg[ks], zacc[dt][pt], 0, 0, 0);
      }
    }
    __syncthreads();
  }

  #pragma unroll
  for (int dt = 0; dt < 2; ++dt) {
    int db0 = 2 * (wv * 32 + dt * 16 + lg * 4);
    #pragma unroll
    for (int pt = 0; pt < 4; ++pt) {
      int p = pt * 16 + lr;
      uint2 pk;
      pk.x = (unsigned)f2b(zacc[dt][pt][0]) | ((unsigned)f2b(zacc[dt][pt][1]) << 16);
      pk.y = (unsigned)f2b(zacc[dt][pt][2]) | ((unsigned)f2b(zacc[dt][pt][3]) << 16);
      *reinterpret_cast<uint2*>(RT + p * 256 + (db0 ^ ((p & 7) << 4))) = pk;
    }
  }
  __syncthreads();

  const float inv_scale = 0.08838834764831845f;
  float* ob = Out + (size_t)b * 16384 + ph * 64;
  #pragma unroll
  for (int nt = 0; nt < 2; ++nt) {
    #pragma unroll
    for (int pt = 0; pt < 4; ++pt) {
      int p = pt * 16 + lr;
      bf16x8 bz[4];
      #pragma unroll
      for (int ks = 0; ks < 4; ++ks)
        bz[ks] = *reinterpret_cast<const bf16x8*>(
            RT + p * 256 + ((ks * 64 + lg * 16) ^ ((p & 7) << 4)));
      f32x4 oa = {0.f, 0.f, 0.f, 0.f};
      #pragma unroll
      for (int ks = 0; ks < 4; ++ks)
        oa = __builtin_amdgcn_mfma_f32_16x16x32_bf16(fa[nt][ks], bz[ks], oa, 0, 0, 0);
      int n0 = wv * 32 + nt * 16 + lg * 4;
      #pragma unroll
      for (int r = 0; r < 4; ++r)
        ob[(size_t)(n0 + r) * 128 + p] = oa[r] * inv_scale;
    }
  }
}

extern "C" void kernel_launch(void* const* d_in, const int* in_sizes, int n_in,
                              void* d_out, int out_size, void* d_ws, size_t ws_size,
                              hipStream_t stream) {
  const float* flows = (const float*)d_in[0];
  const float* g1_wl = (const float*)d_in[10];
  const float* g1_bl = (const float*)d_in[11];
  const float* g1_wr = (const float*)d_in[12];
  const float* g2_wl = (const float*)d_in[13];
  const float* g2_bl = (const float*)d_in[14];
  const float* g2_wr = (const float*)d_in[15];
  const float* g3_wl = (const float*)d_in[16];
  const float* g3_bl = (const float*)d_in[17];
  const float* g3_wr = (const float*)d_in[18];
  const float* g4_wl = (const float*)d_in[19];
  const float* g4_bl = (const float*)d_in[20];
  const float* g4_wr = (const float*)d_in[21];
  const float* qsa   = (const float*)d_in[24];
  const float* ksa   = (const float*)d_in[25];
  const float* s2w   = (const float*)d_in[27];
  float* out = (float*)d_out;
  char* wsb  = (char*)d_ws;

  // workspace layout (bytes)
  ushort* FB16 = (ushort*)(wsb);                 // 32768*128 bf16 = 8388608
  ushort* SB   = (ushort*)(wsb + 8388608);       // 131072 bf16
  ushort* WL   = (ushort*)(wsb + 8650752);       // 98304 bf16
  ushort* WR   = (ushort*)(wsb + 8847360);
  ushort* MBT  = (ushort*)(wsb + 9043968);       // 128*1024 bf16

  prep_all_k<<<896, 256, 0, stream>>>(s2w,
                                      g1_wl, g2_wl, g3_wl, g4_wl,
                                      g1_wr, g2_wr, g3_wr, g4_wr,
                                      SB, WL, WR);
  prep_mb_k<<<8, 256, 0, stream>>>(qsa, ksa, MBT);
  chain0_k<<<1, 1024, 0, stream>>>(flows, WL, WR, g1_bl, g2_bl, g3_bl, g4_bl, FB16);
  sage_fused<<<510, 256, 0, stream>>>(flows, WR, g1_bl, g2_bl, g3_bl, g4_bl, FB16);
  attn_fused<<<512, 256, 0, stream>>>(FB16, MBT, SB, out);
}

// Round 16
// 243.352 us; speedup vs baseline: 1.4147x; 1.0567x over previous
//
#include <hip/hip_runtime.h>
#include <math.h>

// Model_6150393168181 — fully bf16-MFMA pipeline, 3 launches.
//   prep_all_k: weight bf16 conversions (SB reorder, WL/WR)      [dep: none]
//   mega_k:     blocks 0..509 sage rows 128.., block 510 = batch-0 chain (writes F[0:128]),
//               blocks 511..518 = prep_mb (MBT)                  [dep: prep_all]
//   attn_fused: Z-route attention                                 [dep: mega]
// Math: out[b] = f @ Z / sqrt(128), Z = sum_w MB_w^T (f^T SB_w^T);
//   MB_w[e][d] = sum_o' ksa[w,o',e] qsa[w,o',d];  f = rms(relu(SAGE4(rms(flows))));
//   SAGE agg (rows 0..127 only): corr_l = L @ (s.X_l @ wl_l^T), L[n][i]=(i<n)/max(n,1).

typedef __attribute__((ext_vector_type(8))) short bf16x8;
typedef __attribute__((ext_vector_type(4))) float f32x4;

__device__ inline ushort f2b(float x) {
  unsigned u = __builtin_bit_cast(unsigned, x);
  unsigned r = (u + 0x7fffu + ((u >> 16) & 1u)) >> 16;
  return (ushort)r;
}

// ---------------- prep: SB reorder + SAGE weight conversions ----------------
__global__ __launch_bounds__(256) void prep_all_k(
    const float* __restrict__ s2w,
    const float* __restrict__ wl1, const float* __restrict__ wl2,
    const float* __restrict__ wl3, const float* __restrict__ wl4,
    const float* __restrict__ wr1, const float* __restrict__ wr2,
    const float* __restrict__ wr3, const float* __restrict__ wr4,
    ushort* __restrict__ SB, ushort* __restrict__ WL, ushort* __restrict__ WR) {
  int i = blockIdx.x * 256 + threadIdx.x;
  if (i < 131072) {
    int w = i >> 14, p = (i >> 7) & 127, m = i & 127;
    SB[i] = f2b(s2w[p * 1024 + m * 8 + w]);
    return;
  }
  i -= 131072;
  if (i < 98304) {
    float v, u;
    if      (i < 16384) { v = wl1[i];         u = wr1[i]; }
    else if (i < 49152) { v = wl2[i - 16384]; u = wr2[i - 16384]; }
    else if (i < 81920) { v = wl3[i - 49152]; u = wr3[i - 49152]; }
    else                { v = wl4[i - 81920]; u = wr4[i - 81920]; }
    WL[i] = f2b(v);
    WR[i] = f2b(u);
  }
}

// ---------------- sage helpers (pointer-based LDS) ----------------
__device__ inline void stage_flows64(const float* __restrict__ flows, int blk,
                                     char* Xt, float* sArr, int wv, int lane) {
  int r2 = lane >> 5;
  int c4 = lane & 31;
  #pragma unroll
  for (int it = 0; it < 8; ++it) {
    int rowbase = wv * 16 + it * 2;
    const float4 v = *reinterpret_cast<const float4*>(
        flows + ((size_t)blk * 64 + rowbase) * 128 + lane * 4);
    int row = rowbase + r2;
    float ss = v.x * v.x + v.y * v.y + v.z * v.z + v.w * v.w;
    ss += __shfl_xor(ss, 16); ss += __shfl_xor(ss, 8);
    ss += __shfl_xor(ss, 4);  ss += __shfl_xor(ss, 2); ss += __shfl_xor(ss, 1);
    uint2 pk;
    pk.x = (unsigned)f2b(v.x) | ((unsigned)f2b(v.y) << 16);
    pk.y = (unsigned)f2b(v.z) | ((unsigned)f2b(v.w) << 16);
    *reinterpret_cast<uint2*>(Xt + row * 256 + ((c4 * 8) ^ ((row & 7) << 4))) = pk;
    if (c4 == 0) sArr[row] = rsqrtf(ss * (1.0f / 128.0f));
  }
}

template <int K, int N>
__device__ inline void sage_layer_mid64(char* Xt, const float* sP, float* sN,
                                        const ushort* __restrict__ Wr,
                                        const float* __restrict__ bias,
                                        int wv, int lr, int lg) {
  __syncthreads();
  bf16x8 a[K / 32];
  float sr[4];
  int rowA = wv * 16 + lr;
  #pragma unroll
  for (int ks = 0; ks < K / 32; ++ks)
    a[ks] = *reinterpret_cast<const bf16x8*>(
        Xt + rowA * (K * 2) + ((ks * 64 + lg * 16) ^ ((rowA & 7) << 4)));
  #pragma unroll
  for (int rr = 0; rr < 4; ++rr) sr[rr] = sP[wv * 16 + 4 * lg + rr];
  __syncthreads();
  float ssq[4] = {0.f, 0.f, 0.f, 0.f};
  #pragma unroll
  for (int nt = 0; nt < N / 16; ++nt) {
    int col = nt * 16 + lr;
    bf16x8 b[K / 32];
    #pragma unroll
    for (int ks = 0; ks < K / 32; ++ks)
      b[ks] = *reinterpret_cast<const bf16x8*>(Wr + col * K + ks * 32 + lg * 8);
    f32x4 acc = {0.f, 0.f, 0.f, 0.f};
    #pragma unroll
    for (int ks = 0; ks < K / 32; ++ks)
      acc = __builtin_amdgcn_mfma_f32_16x16x32_bf16(a[ks], b[ks], acc, 0, 0, 0);
    float bb = bias[col];
    #pragma unroll
    for (int rr = 0; rr < 4; ++rr) {
      int row = wv * 16 + 4 * lg + rr;
      float y = acc[rr] * sr[rr] + bb;
      *reinterpret_cast<ushort*>(Xt + row * (N * 2) + ((col * 2) ^ ((row & 7) << 4))) = f2b(y);
      ssq[rr] += y * y;
    }
  }
  #pragma unroll
  for (int rr = 0; rr < 4; ++rr) {
    float ss = ssq[rr];
    ss += __shfl_xor(ss, 1); ss += __shfl_xor(ss, 2);
    ss += __shfl_xor(ss, 4); ss += __shfl_xor(ss, 8);
    if (lr == 0) sN[wv * 16 + 4 * lg + rr] = 1.0f / fmaxf(sqrtf(ss), 1e-12f);
  }
}

__device__ inline void sage_layer_last64(char* Xt, const float* sP,
                                         const ushort* __restrict__ Wr,
                                         const float* __restrict__ bias,
                                         int wv, int lr, int lg,
                                         ushort* __restrict__ Fg, int blk) {
  __syncthreads();
  bf16x8 a[4];
  float sr[4];
  int rowA = wv * 16 + lr;
  #pragma unroll
  for (int ks = 0; ks < 4; ++ks)
    a[ks] = *reinterpret_cast<const bf16x8*>(
        Xt + rowA * 256 + ((ks * 64 + lg * 16) ^ ((rowA & 7) << 4)));
  #pragma unroll
  for (int rr = 0; rr < 4; ++rr) sr[rr] = sP[wv * 16 + 4 * lg + rr];
  __syncthreads();
  float yreg[8][4];
  float ssq[4] = {0.f, 0.f, 0.f, 0.f};  // sum relu(y)^2 (inv-cancel identity)
  #pragma unroll
  for (int nt = 0; nt < 8; ++nt) {
    int col = nt * 16 + lr;
    bf16x8 b[4];
    #pragma unroll
    for (int ks = 0; ks < 4; ++ks)
      b[ks] = *reinterpret_cast<const bf16x8*>(Wr + col * 128 + ks * 32 + lg * 8);
    f32x4 acc = {0.f, 0.f, 0.f, 0.f};
    #pragma unroll
    for (int ks = 0; ks < 4; ++ks)
      acc = __builtin_amdgcn_mfma_f32_16x16x32_bf16(a[ks], b[ks], acc, 0, 0, 0);
    float bb = bias[col];
    #pragma unroll
    for (int rr = 0; rr < 4; ++rr) {
      float y = acc[rr] * sr[rr] + bb;
      yreg[nt][rr] = y;
      float v = fmaxf(y, 0.f);
      ssq[rr] += v * v;
    }
  }
  float sc[4];
  #pragma unroll
  for (int rr = 0; rr < 4; ++rr) {
    float ss = ssq[rr];
    ss += __shfl_xor(ss, 1); ss += __shfl_xor(ss, 2);
    ss += __shfl_xor(ss, 4); ss += __shfl_xor(ss, 8);
    sc[rr] = sqrtf(128.0f / fmaxf(ss, 1e-20f));
  }
  #pragma unroll
  for (int nt = 0; nt < 8; ++nt)
    #pragma unroll
    for (int rr = 0; rr < 4; ++rr) {
      int row = wv * 16 + 4 * lg + rr;
      Fg[((size_t)blk * 64 + row) * 128 + nt * 16 + lr] = f2b(fmaxf(yreg[nt][rr], 0.f) * sc[rr]);
    }
}

// ---------------- mega kernel ----------------
__global__ __launch_bounds__(256, 2) void mega_k(
    const float* __restrict__ flows,
    const float* __restrict__ qsa, const float* __restrict__ ksa,
    const ushort* __restrict__ WL, const ushort* __restrict__ WR,
    const float* __restrict__ bl1, const float* __restrict__ bl2,
    const float* __restrict__ bl3, const float* __restrict__ bl4,
    ushort* __restrict__ Fg, ushort* __restrict__ MBT, ushort* __restrict__ X2Tg) {
  __shared__ char L[66560];   // 65 KB: [Xt 32K][C0 32K][sA 512][sB 512]
  const int bid = blockIdx.x;
  const int tid = threadIdx.x;
  const int lane = tid & 63, wv = tid >> 6, lr = lane & 15, lg = lane >> 4;

  if (bid < 510) {
    // ---------------- sage path: rows 128..32767 ----------------
    char* Xt = L;
    float* sA = (float*)(L + 65536);
    float* sB = (float*)(L + 66048);
    int blk = bid + 2;
    stage_flows64(flows, blk, Xt, sA, wv, lane);
    sage_layer_mid64<128, 128>(Xt, sA, sB, WR + 0,     bl1, wv, lr, lg);
    sage_layer_mid64<128, 256>(Xt, sB, sA, WR + 16384, bl2, wv, lr, lg);
    sage_layer_mid64<256, 128>(Xt, sA, sB, WR + 49152, bl3, wv, lr, lg);
    sage_layer_last64(Xt, sB, WR + 81920, bl4, wv, lr, lg, Fg, blk);
    return;
  }

  if (bid >= 511) {
    // ---------------- prep_mb path: MBT[d][(w,e)] ----------------
    char* QT  = L;            // QT[d][o']
    char* KTm = L + 32768;    // KTm[e][o']
    int w = bid - 511;
    const float* qw = qsa + (size_t)w * 16384;
    const float* kw = ksa + (size_t)w * 16384;
    for (int e = tid; e < 16384; e += 256) {
      int op = e >> 7, c = e & 127;
      int off = c * 256 + ((op * 2) ^ ((c & 7) << 4));
      *reinterpret_cast<ushort*>(QT + off)  = f2b(qw[e]);
      *reinterpret_cast<ushort*>(KTm + off) = f2b(kw[e]);
    }
    __syncthreads();
    #pragma unroll
    for (int rt = 0; rt < 2; ++rt) {
      int e = wv * 32 + rt * 16 + lr;
      bf16x8 a[4];
      #pragma unroll
      for (int ks = 0; ks < 4; ++ks)
        a[ks] = *reinterpret_cast<const bf16x8*>(KTm + e * 256 + ((ks * 64 + lg * 16) ^ ((e & 7) << 4)));
      #pragma unroll
      for (int ct = 0; ct < 8; ++ct) {
        int d = ct * 16 + lr;
        bf16x8 bq[4];
        #pragma unroll
        for (int ks = 0; ks < 4; ++ks)
          bq[ks] = *reinterpret_cast<const bf16x8*>(QT + d * 256 + ((ks * 64 + lg * 16) ^ ((d & 7) << 4)));
        f32x4 acc = {0.f, 0.f, 0.f, 0.f};
        #pragma unroll
        for (int ks = 0; ks < 4; ++ks)
          acc = __builtin_amdgcn_mfma_f32_16x16x32_bf16(a[ks], bq[ks], acc, 0, 0, 0);
        uint2 pk;
        pk.x = (unsigned)f2b(acc[0]) | ((unsigned)f2b(acc[1]) << 16);
        pk.y = (unsigned)f2b(acc[2]) | ((unsigned)f2b(acc[3]) << 16);
        *reinterpret_cast<uint2*>(&MBT[(size_t)(ct * 16 + lr) * 1024 + w * 128 + wv * 32 + rt * 16 + lg * 4]) = pk;
      }
    }
    return;
  }

  // ---------------- chain path (bid == 510): batch-0 rows 0..127 with corr ----------------
  char* Xt = L;
  char* C0 = L + 32768;
  float* sA = (float*)(L + 65536);
  float* sB = (float*)(L + 66048);

  // stage flows[0:128] -> Xt (swizzled bf16) + sA rms scales
  #pragma unroll
  for (int it = 0; it < 16; ++it) {
    int idx = tid + it * 256;
    int row = idx >> 5, c4 = idx & 31;
    const float4 v = *reinterpret_cast<const float4*>(flows + (size_t)row * 128 + c4 * 4);
    float ss = v.x * v.x + v.y * v.y + v.z * v.z + v.w * v.w;
    ss += __shfl_xor(ss, 16); ss += __shfl_xor(ss, 8);
    ss += __shfl_xor(ss, 4);  ss += __shfl_xor(ss, 2); ss += __shfl_xor(ss, 1);
    uint2 pk;
    pk.x = (unsigned)f2b(v.x) | ((unsigned)f2b(v.y) << 16);
    pk.y = (unsigned)f2b(v.z) | ((unsigned)f2b(v.w) << 16);
    *reinterpret_cast<uint2*>(Xt + row * 256 + ((c4 * 8) ^ ((row & 7) << 4))) = pk;
    if ((lane & 31) == 0) sA[row] = rsqrtf(ss * (1.0f / 128.0f));
  }

  // triangular L fragments (shared by all layers)
  bf16x8 aL[2][4];
  #pragma unroll
  for (int mt = 0; mt < 2; ++mt) {
    int rowL = wv * 32 + mt * 16 + lr;
    ushort iv = f2b(1.0f / (float)(rowL > 1 ? rowL : 1));
    #pragma unroll
    for (int ks = 0; ks < 4; ++ks)
      #pragma unroll
      for (int j = 0; j < 8; ++j) {
        int k = ks * 32 + lg * 8 + j;
        aL[mt][ks][j] = (short)((k < rowL) ? iv : 0);
      }
  }

  // ===== L1: K=128 Xt -> N=128 Xt (in place), scales sA -> sB =====
  {
    __syncthreads();
    bf16x8 a[2][4];
    float sr[2][4];
    #pragma unroll
    for (int mt = 0; mt < 2; ++mt) {
      int rowA = wv * 32 + mt * 16 + lr;
      #pragma unroll
      for (int ks = 0; ks < 4; ++ks)
        a[mt][ks] = *reinterpret_cast<const bf16x8*>(
            Xt + rowA * 256 + ((ks * 64 + lg * 16) ^ ((rowA & 7) << 4)));
      #pragma unroll
      for (int rr = 0; rr < 4; ++rr) sr[mt][rr] = sA[wv * 32 + mt * 16 + 4 * lg + rr];
    }
    // pass1 -> C0
    #pragma unroll
    for (int nt = 0; nt < 8; ++nt) {
      int col = nt * 16 + lr;
      bf16x8 b[4];
      #pragma unroll
      for (int ks = 0; ks < 4; ++ks)
        b[ks] = *reinterpret_cast<const bf16x8*>(WL + col * 128 + ks * 32 + lg * 8);
      #pragma unroll
      for (int mt = 0; mt < 2; ++mt) {
        f32x4 acc = {0.f, 0.f, 0.f, 0.f};
        #pragma unroll
        for (int ks = 0; ks < 4; ++ks)
          acc = __builtin_amdgcn_mfma_f32_16x16x32_bf16(a[mt][ks], b[ks], acc, 0, 0, 0);
        uint2 pk;
        pk.x = (unsigned)f2b(acc[0] * sr[mt][0]) | ((unsigned)f2b(acc[1] * sr[mt][1]) << 16);
        pk.y = (unsigned)f2b(acc[2] * sr[mt][2]) | ((unsigned)f2b(acc[3] * sr[mt][3]) << 16);
        *reinterpret_cast<uint2*>(C0 + col * 256 + ((2 * (wv * 32 + mt * 16 + lg * 4)) ^ ((col & 7) << 4))) = pk;
      }
    }
    __syncthreads();
    // pass2: y = s.X@Wr^T + b + L@C0 -> Xt in place
    float ssq[2][4] = {{0.f,0.f,0.f,0.f},{0.f,0.f,0.f,0.f}};
    #pragma unroll
    for (int nt = 0; nt < 8; ++nt) {
      int col = nt * 16 + lr;
      bf16x8 bc[4], bw[4];
      #pragma unroll
      for (int ks = 0; ks < 4; ++ks) {
        bc[ks] = *reinterpret_cast<const bf16x8*>(C0 + col * 256 + ((ks * 64 + lg * 16) ^ ((col & 7) << 4)));
        bw[ks] = *reinterpret_cast<const bf16x8*>(WR + col * 128 + ks * 32 + lg * 8);
      }
      float bb = bl1[col];
      #pragma unroll
      for (int mt = 0; mt < 2; ++mt) {
        f32x4 cacc = {0.f, 0.f, 0.f, 0.f}, acc = {0.f, 0.f, 0.f, 0.f};
        #pragma unroll
        for (int ks = 0; ks < 4; ++ks) {
          cacc = __builtin_amdgcn_mfma_f32_16x16x32_bf16(aL[mt][ks], bc[ks], cacc, 0, 0, 0);
          acc  = __builtin_amdgcn_mfma_f32_16x16x32_bf16(a[mt][ks],  bw[ks], acc,  0, 0, 0);
        }
        #pragma unroll
        for (int rr = 0; rr < 4; ++rr) {
          int row = wv * 32 + mt * 16 + lg * 4 + rr;
          float y = acc[rr] * sr[mt][rr] + bb + cacc[rr];
          *reinterpret_cast<ushort*>(Xt + row * 256 + ((col * 2) ^ ((row & 7) << 4))) = f2b(y);
          ssq[mt][rr] += y * y;
        }
      }
    }
    #pragma unroll
    for (int mt = 0; mt < 2; ++mt)
      #pragma unroll
      for (int rr = 0; rr < 4; ++rr) {
        float ss = ssq[mt][rr];
        ss += __shfl_xor(ss, 1); ss += __shfl_xor(ss, 2);
        ss += __shfl_xor(ss, 4); ss += __shfl_xor(ss, 8);
        if (lr == 0) sB[wv * 32 + mt * 16 + 4 * lg + rr] = 1.0f / fmaxf(sqrtf(ss), 1e-12f);
      }
  }

  // ===== L2: K=128 Xt -> N=256 X2Tg (global, transposed), scales sB -> sA =====
  {
    __syncthreads();
    bf16x8 a[2][4];
    float sr[2][4];
    #pragma unroll
    for (int mt = 0; mt < 2; ++mt) {
      int rowA = wv * 32 + mt * 16 + lr;
      #pragma unroll
      for (int ks = 0; ks < 4; ++ks)
        a[mt][ks] = *reinterpret_cast<const bf16x8*>(
            Xt + rowA * 256 + ((ks * 64 + lg * 16) ^ ((rowA & 7) << 4)));
      #pragma unroll
      for (int rr = 0; rr < 4; ++rr) sr[mt][rr] = sB[wv * 32 + mt * 16 + 4 * lg + rr];
    }
    float ssq[2][4] = {{0.f,0.f,0.f,0.f},{0.f,0.f,0.f,0.f}};
    for (int half = 0; half < 2; ++half) {
      __syncthreads();   // C0 free (prev pass2 reads done)
      #pragma unroll
      for (int nt = 0; nt < 8; ++nt) {
        int coll = nt * 16 + lr, colg = half * 128 + coll;
        bf16x8 b[4];
        #pragma unroll
        for (int ks = 0; ks < 4; ++ks)
          b[ks] = *reinterpret_cast<const bf16x8*>(WL + 16384 + colg * 128 + ks * 32 + lg * 8);
        #pragma unroll
        for (int mt = 0; mt < 2; ++mt) {
          f32x4 acc = {0.f, 0.f, 0.f, 0.f};
          #pragma unroll
          for (int ks = 0; ks < 4; ++ks)
            acc = __builtin_amdgcn_mfma_f32_16x16x32_bf16(a[mt][ks], b[ks], acc, 0, 0, 0);
          uint2 pk;
          pk.x = (unsigned)f2b(acc[0] * sr[mt][0]) | ((unsigned)f2b(acc[1] * sr[mt][1]) << 16);
          pk.y = (unsigned)f2b(acc[2] * sr[mt][2]) | ((unsigned)f2b(acc[3] * sr[mt][3]) << 16);
          *reinterpret_cast<uint2*>(C0 + coll * 256 + ((2 * (wv * 32 + mt * 16 + lg * 4)) ^ ((coll & 7) << 4))) = pk;
        }
      }
      __syncthreads();
      #pragma unroll
      for (int nt = 0; nt < 8; ++nt) {
        int coll = nt * 16 + lr, colg = half * 128 + coll;
        bf16x8 bc[4], bw[4];
        #pragma unroll
        for (int ks = 0; ks < 4; ++ks) {
          bc[ks] = *reinterpret_cast<const bf16x8*>(C0 + coll * 256 + ((ks * 64 + lg * 16) ^ ((coll & 7) << 4)));
          bw[ks] = *reinterpret_cast<const bf16x8*>(WR + 16384 + colg * 128 + ks * 32 + lg * 8);
        }
        float bb = bl2[colg];
        #pragma unroll
        for (int mt = 0; mt < 2; ++mt) {
          f32x4 cacc = {0.f, 0.f, 0.f, 0.f}, acc = {0.f, 0.f, 0.f, 0.f};
          #pragma unroll
          for (int ks = 0; ks < 4; ++ks) {
            cacc = __builtin_amdgcn_mfma_f32_16x16x32_bf16(aL[mt][ks], bc[ks], cacc, 0, 0, 0);
            acc  = __builtin_amdgcn_mfma_f32_16x16x32_bf16(a[mt][ks],  bw[ks], acc,  0, 0, 0);
          }
          uint2 pk;
          float y0 = acc[0] * sr[mt][0] + bb + cacc[0];
          float y1 = acc[1] * sr[mt][1] + bb + cacc[1];
          float y2 = acc[2] * sr[mt][2] + bb + cacc[2];
          float y3 = acc[3] * sr[mt][3] + bb + cacc[3];
          ssq[mt][0] += y0 * y0; ssq[mt][1] += y1 * y1;
          ssq[mt][2] += y2 * y2; ssq[mt][3] += y3 * y3;
          pk.x = (unsigned)f2b(y0) | ((unsigned)f2b(y1) << 16);
          pk.y = (unsigned)f2b(y2) | ((unsigned)f2b(y3) << 16);
          *reinterpret_cast<uint2*>(&X2Tg[(size_t)colg * 128 + wv * 32 + mt * 16 + lg * 4]) = pk;
        }
      }
    }
    #pragma unroll
    for (int mt = 0; mt < 2; ++mt)
      #pragma unroll
      for (int rr = 0; rr < 4; ++rr) {
        float ss = ssq[mt][rr];
        ss += __shfl_xor(ss, 1); ss += __shfl_xor(ss, 2);
        ss += __shfl_xor(ss, 4); ss += __shfl_xor(ss, 8);
        if (lr == 0) sA[wv * 32 + mt * 16 + 4 * lg + rr] = 1.0f / fmaxf(sqrtf(ss), 1e-12f);
      }
  }

  // ===== L3: K=256 X2Tg -> N=128 Xt, scales sA -> sB =====
  {
    __syncthreads();  // X2Tg writes drained (barrier semantics), sA ready
    // pass1 (per rowtile to bound registers)
    #pragma unroll
    for (int mt = 0; mt < 2; ++mt) {
      int rowA = wv * 32 + mt * 16 + lr;
      bf16x8 a8[8];
      #pragma unroll
      for (int ks = 0; ks < 8; ++ks) {
        union { ushort us[8]; bf16x8 v; } u;
        #pragma unroll
        for (int j = 0; j < 8; ++j)
          u.us[j] = X2Tg[(size_t)(ks * 32 + lg * 8 + j) * 128 + rowA];
        a8[ks] = u.v;
      }
      float srm[4];
      #pragma unroll
      for (int rr = 0; rr < 4; ++rr) srm[rr] = sA[wv * 32 + mt * 16 + 4 * lg + rr];
      #pragma unroll
      for (int nt = 0; nt < 8; ++nt) {
        int col = nt * 16 + lr;
        f32x4 acc = {0.f, 0.f, 0.f, 0.f};
        #pragma unroll
        for (int ks = 0; ks < 8; ++ks) {
          bf16x8 b = *reinterpret_cast<const bf16x8*>(WL + 49152 + col * 256 + ks * 32 + lg * 8);
          acc = __builtin_amdgcn_mfma_f32_16x16x32_bf16(a8[ks], b, acc, 0, 0, 0);
        }
        uint2 pk;
        pk.x = (unsigned)f2b(acc[0] * srm[0]) | ((unsigned)f2b(acc[1] * srm[1]) << 16);
        pk.y = (unsigned)f2b(acc[2] * srm[2]) | ((unsigned)f2b(acc[3] * srm[3]) << 16);
        *reinterpret_cast<uint2*>(C0 + col * 256 + ((2 * (wv * 32 + mt * 16 + lg * 4)) ^ ((col & 7) << 4))) = pk;
      }
    }
    __syncthreads();
    // pass2 per rowtile
    #pragma unroll
    for (int mt = 0; mt < 2; ++mt) {
      int rowA = wv * 32 + mt * 16 + lr;
      bf16x8 a8[8];
      #pragma unroll
      for (int ks = 0; ks < 8; ++ks) {
        union { ushort us[8]; bf16x8 v; } u;
        #pragma unroll
        for (int j = 0; j < 8; ++j)
          u.us[j] = X2Tg[(size_t)(ks * 32 + lg * 8 + j) * 128 + rowA];
        a8[ks] = u.v;
      }
      float srm[4];
      #pragma unroll
      for (int rr = 0; rr < 4; ++rr) srm[rr] = sA[wv * 32 + mt * 16 + 4 * lg + rr];
      float ssq[4] = {0.f, 0.f, 0.f, 0.f};
      #pragma unroll
      for (int nt = 0; nt < 8; ++nt) {
        int col = nt * 16 + lr;
        bf16x8 bc[4];
        #pragma unroll
        for (int ks = 0; ks < 4; ++ks)
          bc[ks] = *reinterpret_cast<const bf16x8*>(C0 + col * 256 + ((ks * 64 + lg * 16) ^ ((col & 7) << 4)));
        f32x4 cacc = {0.f, 0.f, 0.f, 0.f}, acc = {0.f, 0.f, 0.f, 0.f};
        #pragma unroll
        for (int ks = 0; ks < 4; ++ks)
          cacc = __builtin_amdgcn_mfma_f32_16x16x32_bf16(aL[mt][ks], bc[ks], cacc, 0, 0, 0);
        #pragma unroll
        for (int ks = 0; ks < 8; ++ks) {
          bf16x8 b = *reinterpret_cast<const bf16x8*>(WR + 49152 + col * 256 + ks * 32 + lg * 8);
          acc = __builtin_amdgcn_mfma_f32_16x16x32_bf16(a8[ks], b, acc, 0, 0, 0);
        }
        float bb = bl3[col];
        #pragma unroll
        for (int rr = 0; rr < 4; ++rr) {
          int row = wv * 32 + mt * 16 + lg * 4 + rr;
          float y = acc[rr] * srm[rr] + bb + cacc[rr];
          *reinterpret_cast<ushort*>(Xt + row * 256 + ((col * 2) ^ ((row & 7) << 4))) = f2b(y);
          ssq[rr] += y * y;
        }
      }
      #pragma unroll
      for (int rr = 0; rr < 4; ++rr) {
        float ss = ssq[rr];
        ss += __shfl_xor(ss, 1); ss += __shfl_xor(ss, 2);
        ss += __shfl_xor(ss, 4); ss += __shfl_xor(ss, 8);
        if (lr == 0) sB[wv * 32 + mt * 16 + 4 * lg + rr] = 1.0f / fmaxf(sqrtf(ss), 1e-12f);
      }
    }
  }

  // ===== L4: K=128 Xt -> N=128, epilogue L2->relu->rms -> Fg rows 0..127 =====
  {
    __syncthreads();
    bf16x8 a[2][4];
    float sr[2][4];
    #pragma unroll
    for (int mt = 0; mt < 2; ++mt) {
      int rowA = wv * 32 + mt * 16 + lr;
      #pragma unroll
      for (int ks = 0; ks < 4; ++ks)
        a[mt][ks] = *reinterpret_cast<const bf16x8*>(
            Xt + rowA * 256 + ((ks * 64 + lg * 16) ^ ((rowA & 7) << 4)));
      #pragma unroll
      for (int rr = 0; rr < 4; ++rr) sr[mt][rr] = sB[wv * 32 + mt * 16 + 4 * lg + rr];
    }
    // pass1 -> C0
    #pragma unroll
    for (int nt = 0; nt < 8; ++nt) {
      int col = nt * 16 + lr;
      bf16x8 b[4];
      #pragma unroll
      for (int ks = 0; ks < 4; ++ks)
        b[ks] = *reinterpret_cast<const bf16x8*>(WL + 81920 + col * 128 + ks * 32 + lg * 8);
      #pragma unroll
      for (int mt = 0; mt < 2; ++mt) {
        f32x4 acc = {0.f, 0.f, 0.f, 0.f};
        #pragma unroll
        for (int ks = 0; ks < 4; ++ks)
          acc = __builtin_amdgcn_mfma_f32_16x16x32_bf16(a[mt][ks], b[ks], acc, 0, 0, 0);
        uint2 pk;
        pk.x = (unsigned)f2b(acc[0] * sr[mt][0]) | ((unsigned)f2b(acc[1] * sr[mt][1]) << 16);
        pk.y = (unsigned)f2b(acc[2] * sr[mt][2]) | ((unsigned)f2b(acc[3] * sr[mt][3]) << 16);
        *reinterpret_cast<uint2*>(C0 + col * 256 + ((2 * (wv * 32 + mt * 16 + lg * 4)) ^ ((col & 7) << 4))) = pk;
      }
    }
    __syncthreads();
    // pass2 per rowtile with relu-rms epilogue (inv cancels)
    #pragma unroll
    for (int mt = 0; mt < 2; ++mt) {
      float yreg[8][4];
      float ssqR[4] = {0.f, 0.f, 0.f, 0.f};
      #pragma unroll
      for (int nt = 0; nt < 8; ++nt) {
        int col = nt * 16 + lr;
        bf16x8 bc[4], bw[4];
        #pragma unroll
        for (int ks = 0; ks < 4; ++ks) {
          bc[ks] = *reinterpret_cast<const bf16x8*>(C0 + col * 256 + ((ks * 64 + lg * 16) ^ ((col & 7) << 4)));
          bw[ks] = *reinterpret_cast<const bf16x8*>(WR + 81920 + col * 128 + ks * 32 + lg * 8);
        }
        f32x4 cacc = {0.f, 0.f, 0.f, 0.f}, acc = {0.f, 0.f, 0.f, 0.f};
        #pragma unroll
        for (int ks = 0; ks < 4; ++ks) {
          cacc = __builtin_amdgcn_mfma_f32_16x16x32_bf16(aL[mt][ks], bc[ks], cacc, 0, 0, 0);
          acc  = __builtin_amdgcn_mfma_f32_16x16x32_bf16(a[mt][ks],  bw[ks], acc,  0, 0, 0);
        }
        float bb = bl4[col];
        #pragma unroll
        for (int rr = 0; rr < 4; ++rr) {
          float y = acc[rr] * sr[mt][rr] + bb + cacc[rr];
          yreg[nt][rr] = y;
          float v = fmaxf(y, 0.f);
          ssqR[rr] += v * v;
        }
      }
      float sc[4];
      #pragma unroll
      for (int rr = 0; rr < 4; ++rr) {
        float ss = ssqR[rr];
        ss += __shfl_xor(ss, 1); ss += __shfl_xor(ss, 2);
        ss += __shfl_xor(ss, 4); ss += __shfl_xor(ss, 8);
        sc[rr] = sqrtf(128.0f / fmaxf(ss, 1e-20f));
      }
      #pragma unroll
      for (int nt = 0; nt < 8; ++nt)
        #pragma unroll
        for (int rr = 0; rr < 4; ++rr) {
          int row = wv * 32 + mt * 16 + 4 * lg + rr;
          Fg[(size_t)row * 128 + nt * 16 + lr] = f2b(fmaxf(yreg[nt][rr], 0.f) * sc[rr]);
        }
    }
  }
}

// ---------------- fused attention (Z-route): 512 blocks = 256 b x 2 p-halves ----------------
__global__ __launch_bounds__(256, 3) void attn_fused(
    const ushort* __restrict__ F, const ushort* __restrict__ MBT,
    const ushort* __restrict__ SB, float* __restrict__ Out) {
  __shared__ char FT[32768];
  __shared__ char RT[16384];

  const int bq = blockIdx.x;
  const int b = bq >> 1, ph = bq & 1;
  const int tid = threadIdx.x;
  const int l = tid & 63, wv = tid >> 6;
  const int lr = l & 15, lg = l >> 4;

  const ushort* Fb = F + (size_t)b * 16384;

  #pragma unroll
  for (int it = 0; it < 8; ++it) {
    int idx = tid + it * 256;
    int m = idx >> 4, eg = idx & 15;
    uint4 v = *reinterpret_cast<const uint4*>(Fb + m * 128 + eg * 8);
    const ushort* pv = reinterpret_cast<const ushort*>(&v);
    #pragma unroll
    for (int j = 0; j < 8; ++j) {
      int e = eg * 8 + j;
      *reinterpret_cast<ushort*>(FT + e * 256 + ((m * 2) ^ ((e & 7) << 4))) = pv[j];
    }
  }

  bf16x8 fa[2][4];
  #pragma unroll
  for (int nt = 0; nt < 2; ++nt) {
    int n = wv * 32 + nt * 16 + lr;
    #pragma unroll
    for (int ks = 0; ks < 4; ++ks)
      fa[nt][ks] = *reinterpret_cast<const bf16x8*>(Fb + n * 128 + ks * 32 + lg * 8);
  }
  __syncthreads();

  f32x4 zacc[2][4];
  #pragma unroll
  for (int dt = 0; dt < 2; ++dt)
    #pragma unroll
    for (int pt = 0; pt < 4; ++pt) zacc[dt][pt] = f32x4{0.f, 0.f, 0.f, 0.f};

  for (int w = 0; w < 8; ++w) {
    const ushort* sb = SB + w * 16384 + ph * 64 * 128;

    #pragma unroll
    for (int et = 0; et < 2; ++et) {
      int e = wv * 32 + et * 16 + lr;
      bf16x8 af[4];
      #pragma unroll
      for (int ks = 0; ks < 4; ++ks)
        af[ks] = *reinterpret_cast<const bf16x8*>(
            FT + e * 256 + ((ks * 64 + lg * 16) ^ ((e & 7) << 4)));
      #pragma unroll
      for (int pt = 0; pt < 4; ++pt) {
        int p = pt * 16 + lr;
        bf16x8 bs[4];
        #pragma unroll
        for (int ks = 0; ks < 4; ++ks)
          bs[ks] = *reinterpret_cast<const bf16x8*>(sb + p * 128 + ks * 32 + lg * 8);
        f32x4 rr = {0.f, 0.f, 0.f, 0.f};
        #pragma unroll
        for (int ks = 0; ks < 4; ++ks)
          rr = __builtin_amdgcn_mfma_f32_16x16x32_bf16(af[ks], bs[ks], rr, 0, 0, 0);
        int eb0 = 2 * (wv * 32 + et * 16 + lg * 4);
        uint2 pk;
        pk.x = (unsigned)f2b(rr[0]) | ((unsigned)f2b(rr[1]) << 16);
        pk.y = (unsigned)f2b(rr[2]) | ((unsigned)f2b(rr[3]) << 16);
        *reinterpret_cast<uint2*>(RT + p * 256 + (eb0 ^ ((p & 7) << 4))) = pk;
      }
    }
    __syncthreads();

    #pragma unroll
    for (int dt = 0; dt < 2; ++dt) {
      int d = wv * 32 + dt * 16 + lr;
      bf16x8 mf[4];
      #pragma unroll
      for (int ks = 0; ks < 4; ++ks)
        mf[ks] = *reinterpret_cast<const bf16x8*>(MBT + (size_t)d * 1024 + w * 128 + ks * 32 + lg * 8);
      #pragma unroll
      for (int pt = 0; pt < 4; ++pt) {
        int p = pt * 16 + lr;
        bf16x8 bg[4];
        #pragma unroll
        for (int ks = 0; ks < 4; ++ks)
          bg[ks] = *reinterpret_cast<const bf16x8*>(
              RT + p * 256 + ((ks * 64 + lg * 16) ^ ((p & 7) << 4)));
        #pragma unroll
        for (int ks = 0; ks < 4; ++ks)
          zacc[dt][pt] = __builtin_amdgcn_mfma_f32_16x16x32_bf16(mf[ks], bg[ks], zacc[dt][pt], 0, 0, 0);
      }
    }
    __syncthreads();
  }

  #pragma unroll
  for (int dt = 0; dt < 2; ++dt) {
    int db0 = 2 * (wv * 32 + dt * 16 + lg * 4);
    #pragma unroll
    for (int pt = 0; pt < 4; ++pt) {
      int p = pt * 16 + lr;
      uint2 pk;
      pk.x = (unsigned)f2b(zacc[dt][pt][0]) | ((unsigned)f2b(zacc[dt][pt][1]) << 16);
      pk.y = (unsigned)f2b(zacc[dt][pt][2]) | ((unsigned)f2b(zacc[dt][pt][3]) << 16);
      *reinterpret_cast<uint2*>(RT + p * 256 + (db0 ^ ((p & 7) << 4))) = pk;
    }
  }
  __syncthreads();

  const float inv_scale = 0.08838834764831845f;
  float* ob = Out + (size_t)b * 16384 + ph * 64;
  #pragma unroll
  for (int nt = 0; nt < 2; ++nt) {
    #pragma unroll
    for (int pt = 0; pt < 4; ++pt) {
      int p = pt * 16 + lr;
      bf16x8 bz[4];
      #pragma unroll
      for (int ks = 0; ks < 4; ++ks)
        bz[ks] = *reinterpret_cast<const bf16x8*>(
            RT + p * 256 + ((ks * 64 + lg * 16) ^ ((p & 7) << 4)));
      f32x4 oa = {0.f, 0.f, 0.f, 0.f};
      #pragma unroll
      for (int ks = 0; ks < 4; ++ks)
        oa = __builtin_amdgcn_mfma_f32_16x16x32_bf16(fa[nt][ks], bz[ks], oa, 0, 0, 0);
      int n0 = wv * 32 + nt * 16 + lg * 4;
      #pragma unroll
      for (int r = 0; r < 4; ++r)
        ob[(size_t)(n0 + r) * 128 + p] = oa[r] * inv_scale;
    }
  }
}

extern "C" void kernel_launch(void* const* d_in, const int* in_sizes, int n_in,
                              void* d_out, int out_size, void* d_ws, size_t ws_size,
                              hipStream_t stream) {
  const float* flows = (const float*)d_in[0];
  const float* g1_wl = (const float*)d_in[10];
  const float* g1_bl = (const float*)d_in[11];
  const float* g1_wr = (const float*)d_in[12];
  const float* g2_wl = (const float*)d_in[13];
  const float* g2_bl = (const float*)d_in[14];
  const float* g2_wr = (const float*)d_in[15];
  const float* g3_wl = (const float*)d_in[16];
  const float* g3_bl = (const float*)d_in[17];
  const float* g3_wr = (const float*)d_in[18];
  const float* g4_wl = (const float*)d_in[19];
  const float* g4_bl = (const float*)d_in[20];
  const float* g4_wr = (const float*)d_in[21];
  const float* qsa   = (const float*)d_in[24];
  const float* ksa   = (const float*)d_in[25];
  const float* s2w   = (const float*)d_in[27];
  float* out = (float*)d_out;
  char* wsb  = (char*)d_ws;

  // workspace layout (bytes)
  ushort* FB16 = (ushort*)(wsb);                 // 32768*128 bf16 = 8388608
  ushort* SB   = (ushort*)(wsb + 8388608);       // 131072 bf16
  ushort* WL   = (ushort*)(wsb + 8650752);       // 98304 bf16
  ushort* WR   = (ushort*)(wsb + 8847360);
  ushort* MBT  = (ushort*)(wsb + 9043968);       // 128*1024 bf16
  ushort* X2T  = (ushort*)(wsb + 9306112);       // 256*128 bf16 chain scratch

  prep_all_k<<<896, 256, 0, stream>>>(s2w,
                                      g1_wl, g2_wl, g3_wl, g4_wl,
                                      g1_wr, g2_wr, g3_wr, g4_wr,
                                      SB, WL, WR);
  mega_k<<<519, 256, 0, stream>>>(flows, qsa, ksa, WL, WR,
                                  g1_bl, g2_bl, g3_bl, g4_bl,
                                  FB16, MBT, X2T);
  attn_fused<<<512, 256, 0, stream>>>(FB16, MBT, SB, out);
}